// Round 8
// baseline (130.867 us; speedup 1.0000x reference)
//
#include <hip/hip_runtime.h>
#include <hip/hip_bf16.h>
#include <math.h>

#define LOG2PI_F 1.8378770664093453f

typedef __attribute__((ext_vector_type(8))) short bf16x8;
typedef __attribute__((ext_vector_type(4))) float f32x4;
typedef __attribute__((ext_vector_type(16))) float f32x16;

static __device__ inline short f2bf(float x) {
  __hip_bfloat16 h = __float2bfloat16(x);
  return *reinterpret_cast<short*>(&h);
}
// HW packed f32->bf16 (RNE). Session A/B (r1 vs r2) showed >= sw pack here.
static __device__ inline unsigned cvtpk(float lo, float hi) {
  unsigned r;
  asm("v_cvt_pk_bf16_f32 %0, %1, %2" : "=v"(r) : "v"(lo), "v"(hi));
  return r;
}
static __device__ inline f32x4 mfma16(bf16x8 a, bf16x8 b, f32x4 c) {
  return __builtin_amdgcn_mfma_f32_16x16x32_bf16(a, b, c, 0, 0, 0);
}
static __device__ inline f32x16 mfma32(bf16x8 a, bf16x8 b, f32x16 c) {
  return __builtin_amdgcn_mfma_f32_32x32x16_bf16(a, b, c, 0, 0, 0);
}

// ---------------- K012: fused prep (WTbf + Gt/const_c + XeP) ----------------
__global__ __launch_bounds__(256) void mmm_prep_fused(
    const float* __restrict__ tl, const float* __restrict__ means,
    const float* __restrict__ log_vars, const float* __restrict__ weight_logits,
    const float* __restrict__ X,
    short* __restrict__ WTbf, short* __restrict__ Gt,
    float* __restrict__ const_c, short* __restrict__ XeP) {
  __shared__ float red[4];
  int bid = blockIdx.x;
  int tid = threadIdx.x;

  if (bid < 64) {               // ---- K0 ----
    if (tid < 64) {
      int r = bid, lane = tid;
      float v = tl[r * 64 + lane];
      float mx = v;
      #pragma unroll
      for (int off = 1; off < 64; off <<= 1) mx = fmaxf(mx, __shfl_xor(mx, off));
      float e = expf(v - mx);
      float s = e;
      #pragma unroll
      for (int off = 1; off < 64; off <<= 1) s += __shfl_xor(s, off);
      WTbf[lane * 64 + r] = f2bf(e / s);
    }
    return;
  }

  if (bid < 320) {              // ---- K1 (2 sm per block) ----
    int h = tid >> 7, d = tid & 127;
    int sm = (bid - 64) * 2 + h;
    int s = sm >> 3, m = sm & 7;
    float lv = log_vars[sm * 128 + d];
    float iv = expf(-lv);
    float mu = means[sm * 128 + d];
    float miv = mu * iv;
    Gt[sm * 256 + d] = f2bf(miv);
    Gt[sm * 256 + 128 + d] = f2bf(-0.5f * iv);
    float v = mu * miv + lv;
    #pragma unroll
    for (int off = 1; off < 64; off <<= 1) v += __shfl_xor(v, off);
    if ((tid & 63) == 0) red[tid >> 6] = v;
    __syncthreads();
    if (d == 0) {
      float tot = red[2 * h] + red[2 * h + 1];
      float wl[8];
      float mx = -3.4e38f;
      #pragma unroll
      for (int j = 0; j < 8; ++j) { wl[j] = weight_logits[s * 8 + j]; mx = fmaxf(mx, wl[j]); }
      float sum = 0.f;
      #pragma unroll
      for (int j = 0; j < 8; ++j) sum += expf(wl[j] - mx);
      float lmw = wl[m] - mx - logf(sum);
      const_c[sm] = -0.5f * (tot + 128.0f * LOG2PI_F) + lmw;
    }
    return;
  }

  // ---- K2 ----
  int kbid = bid - 320;
  int q = kbid >> 7;
  int bt = ((kbid & 127) << 8) + tid;
  const float4* src = (const float4*)(X + (size_t)bt * 128 + q * 32);
  float xv[32];
  #pragma unroll
  for (int i = 0; i < 8; ++i) {
    float4 v = src[i];
    xv[4 * i] = v.x; xv[4 * i + 1] = v.y; xv[4 * i + 2] = v.z; xv[4 * i + 3] = v.w;
  }
  size_t base1 = ((size_t)q * 32768 + bt) * 32;
  size_t base2 = ((size_t)(q + 4) * 32768 + bt) * 32;
  int bx = bt & 3;
  #pragma unroll
  for (int g = 0; g < 4; ++g) {
    unsigned w1[4], w2[4];
    #pragma unroll
    for (int j = 0; j < 4; ++j) {
      float a = xv[g * 8 + 2 * j], c = xv[g * 8 + 2 * j + 1];
      w1[j] = cvtpk(a, c);
      w2[j] = cvtpk(a * a, c * c);
    }
    int gs = (g ^ bx) * 8;
    *(uint4*)&XeP[base1 + gs] = *(uint4*)w1;
    *(uint4*)&XeP[base2 + gs] = *(uint4*)w2;
  }
}

// ---------------- K3: MFMA emission GEMM, C[sm=512][bt=64-tile] ------------
__global__ __launch_bounds__(512) void mmm_emis_kernel(
    const short* __restrict__ Gt, const short* __restrict__ XeP,
    const float* __restrict__ const_c,
    float* __restrict__ ehat, float* __restrict__ cmax) {
  __shared__ __align__(16) short Bt[16384];  // 32 KB
  __shared__ __align__(16) float ccs[512];
  __shared__ float wavemax[8][64];
  __shared__ float colmax[64];
  int tid = threadIdx.x;
  int w = tid >> 6, lane = tid & 63, lr = lane & 15, lg = lane >> 4;

  ccs[tid] = const_c[tid];

  bf16x8 gf[4][8];
  #pragma unroll
  for (int rt = 0; rt < 4; ++rt) {
    int row = w * 64 + rt * 16 + lr;
    #pragma unroll
    for (int kc = 0; kc < 8; ++kc)
      gf[rt][kc] = *(const bf16x8*)&Gt[row * 256 + kc * 32 + lg * 8];
  }

  uint4 sreg[4];
  {
    size_t bt0 = (size_t)blockIdx.x * 64;
    #pragma unroll
    for (int r = 0; r < 4; ++r) {
      int ofs = r * 8192 + tid * 16;
      int kb2 = ofs >> 12, rem = ofs & 4095;
      sreg[r] = *(const uint4*)((const char*)XeP + ((size_t)kb2 * 32768 + bt0) * 64 + rem);
    }
  }

  for (int it = 0; it < 2; ++it) {
    int bt0 = (blockIdx.x + it * 256) * 64;
    __syncthreads();
    #pragma unroll
    for (int r = 0; r < 4; ++r)
      *(uint4*)((char*)Bt + r * 8192 + tid * 16) = sreg[r];
    __syncthreads();
    if (it == 0) {
      size_t bt0n = ((size_t)blockIdx.x + 256) * 64;
      #pragma unroll
      for (int r = 0; r < 4; ++r) {
        int ofs = r * 8192 + tid * 16;
        int kb2 = ofs >> 12, rem = ofs & 4095;
        sreg[r] = *(const uint4*)((const char*)XeP + ((size_t)kb2 * 32768 + bt0n) * 64 + rem);
      }
    }

    f32x4 acc[4][4];
    #pragma unroll
    for (int rt = 0; rt < 4; ++rt)
      #pragma unroll
      for (int ct = 0; ct < 4; ++ct)
        acc[rt][ct] = (f32x4){0.f, 0.f, 0.f, 0.f};

    #pragma unroll
    for (int kc = 0; kc < 8; ++kc) {
      bf16x8 bfr[4];
      #pragma unroll
      for (int ct = 0; ct < 4; ++ct) {
        int btL = ct * 16 + lr;
        bfr[ct] = *(const bf16x8*)&Bt[kc * 2048 + btL * 32 + ((lg ^ (btL & 3)) * 8)];
      }
      #pragma unroll
      for (int rt = 0; rt < 4; ++rt)
        #pragma unroll
        for (int ct = 0; ct < 4; ++ct)
          acc[rt][ct] = mfma16(gf[rt][kc], bfr[ct], acc[rt][ct]);
    }

    float lse[4][4];
    #pragma unroll
    for (int rt = 0; rt < 4; ++rt) {
      f32x4 cc = *(f32x4*)&ccs[w * 64 + rt * 16 + lg * 4];
      #pragma unroll
      for (int ct = 0; ct < 4; ++ct) {
        f32x4 v = acc[rt][ct] + cc;
        float mx = fmaxf(fmaxf(v[0], v[1]), fmaxf(v[2], v[3]));
        mx = fmaxf(mx, __shfl_xor(mx, 16));
        float sum = expf(v[0] - mx) + expf(v[1] - mx) + expf(v[2] - mx) + expf(v[3] - mx);
        sum += __shfl_xor(sum, 16);
        lse[rt][ct] = mx + logf(sum);
      }
    }
    #pragma unroll
    for (int ct = 0; ct < 4; ++ct) {
      float cm = fmaxf(fmaxf(lse[0][ct], lse[1][ct]), fmaxf(lse[2][ct], lse[3][ct]));
      cm = fmaxf(cm, __shfl_xor(cm, 32));
      if (lg == 0) wavemax[w][ct * 16 + lr] = cm;
    }
    __syncthreads();
    if (w == 0) {
      float cm = wavemax[0][lane];
      #pragma unroll
      for (int ww = 1; ww < 8; ++ww) cm = fmaxf(cm, wavemax[ww][lane]);
      colmax[lane] = cm;
      cmax[(size_t)bt0 + lane] = cm;
    }
    __syncthreads();
    #pragma unroll
    for (int ct = 0; ct < 4; ++ct) {
      float cm = colmax[ct * 16 + lr];
      #pragma unroll
      for (int rt = 0; rt < 4; ++rt) {
        float v = expf(lse[rt][ct] - cm);
        if (!(lg & 1))
          ehat[((size_t)bt0 + ct * 16 + lr) * 64 + (w * 8 + rt * 2 + (lg >> 1))] = v;
      }
    }
  }
}

// ---------------- K4: per-chunk product, single fat wave, 8-step chunks -----
// r8: 512 chunks x 8 steps. wave-steps/SIMD stays 32 (invariant) but
// residency doubles to 4 waves/SIMD — the untested axis for this
// latency-bound loop (r7 proved issue-count is not the limiter; the
// permlane->mfma-chain->pack dependency stalls need more waves to hide).
// NT is stored as bf16 (state is bf16 anyway) so total NT traffic is
// unchanged despite 2x chunk count. launch_bounds(64,4) caps VGPRs at 128.
__global__ __launch_bounds__(64, 4) void mmm_chunk_kernel(
    const short* __restrict__ WTbf, const float* __restrict__ ehat,
    const float* __restrict__ cmax, short* __restrict__ NTb,
    float* __restrict__ aux) {
  __shared__ __align__(16) float elds[512];  // 8 steps x 64 rows
  int chunk = blockIdx.x, b = blockIdx.y;    // chunk in [0,512)
  int lane = threadIdx.x;
  int l31 = lane & 31, hi = lane >> 5;

  int t0 = (chunk == 0) ? 1 : chunk * 8;
  int nsteps = (chunk == 0) ? 7 : 8;
  const float* eb = ehat + (size_t)b * 4096 * 64;

  // stage e-slice (8 rows x 64 = 2KB, coalesced)
  {
    const float* esrc = eb + (size_t)t0 * 64;
    #pragma unroll
    for (int r = 0; r < 2; ++r)
      *(f32x4*)&elds[r * 256 + lane * 4] = *(const f32x4*)&esrc[r * 256 + lane * 4];
  }

  // A = W^T: af[wi][kb], row = wi*32+l31, k = kb*16 + hi*8 + j
  bf16x8 af[2][4];
  #pragma unroll
  for (int wi = 0; wi < 2; ++wi)
    #pragma unroll
    for (int kb = 0; kb < 4; ++kb)
      af[wi][kb] = *(const bf16x8*)&WTbf[(wi * 32 + l31) * 64 + kb * 16 + hi * 8];

  // packed state: P[s][cm][q][p] = bf16 rows {32cm+8q+4hi+2p, +1} at col s*32+l31
  unsigned P[2][2][4][2];
  #pragma unroll
  for (int s = 0; s < 2; ++s) {
    int col = s * 32 + l31;
    #pragma unroll
    for (int cm = 0; cm < 2; ++cm)
      #pragma unroll
      for (int q = 0; q < 4; ++q)
        #pragma unroll
        for (int p = 0; p < 2; ++p) {
          int row = 32 * cm + 8 * q + 4 * hi + 2 * p;
          unsigned lo = (row == col) ? 0x3F80u : 0u;       // bf16(1.0)
          unsigned h16 = (row + 1 == col) ? 0x3F80u : 0u;
          P[s][cm][q][p] = lo | (h16 << 16);
        }
  }

  __syncthreads();  // e-slice visible wave-wide

  float logscale = 0.f;

  for (int it = 0; it < nsteps; ++it) {
    f32x4 ev[2][4];
    #pragma unroll
    for (int cm = 0; cm < 2; ++cm)
      #pragma unroll
      for (int q = 0; q < 4; ++q)
        ev[cm][q] = *(const f32x4*)&elds[it * 64 + cm * 32 + q * 8 + hi * 4];

    __builtin_amdgcn_s_setprio(1);
    #pragma unroll
    for (int s = 0; s < 2; ++s) {
      // B[kb]: k = kb*16 + 8*hi + j; one permlane32_swap per (quad-pair, p)
      bf16x8 B[4];
      #pragma unroll
      for (int kb = 0; kb < 4; ++kb) {
        int cm = kb >> 1, kbl = kb & 1;
        int4 wrd;
        #pragma unroll
        for (int p = 0; p < 2; ++p) {
          unsigned avv = P[s][cm][2 * kbl + 1][p];
          unsigned bvv = P[s][cm][2 * kbl][p];
          asm("v_permlane32_swap_b32 %0, %1" : "+v"(avv), "+v"(bvv));
          if (p == 0) { wrd.x = (int)bvv; wrd.z = (int)avv; }
          else        { wrd.y = (int)bvv; wrd.w = (int)avv; }
        }
        B[kb] = *(bf16x8*)&wrd;
      }

      f32x16 d0, d1;
      #pragma unroll
      for (int r = 0; r < 16; ++r) { d0[r] = 0.f; d1[r] = 0.f; }
      #pragma unroll
      for (int kb = 0; kb < 4; ++kb) {
        d0 = mfma32(af[0][kb], B[kb], d0);
        d1 = mfma32(af[1][kb], B[kb], d1);
      }

      // P = pack(d * e): reg 4q+s_ -> row 32cm+8q+4hi+s_
      #pragma unroll
      for (int q = 0; q < 4; ++q)
        #pragma unroll
        for (int p = 0; p < 2; ++p) {
          P[s][0][q][p] = cvtpk(d0[4 * q + 2 * p] * ev[0][q][2 * p],
                                d0[4 * q + 2 * p + 1] * ev[0][q][2 * p + 1]);
          P[s][1][q][p] = cvtpk(d1[4 * q + 2 * p] * ev[1][q][2 * p],
                                d1[4 * q + 2 * p + 1] * ev[1][q][2 * p + 1]);
        }
    }
    __builtin_amdgcn_s_setprio(0);

    if ((it & 7) == 7) {  // end-of-chunk rescale (same 8-step cadence as before)
      float m = 0.f;
      #pragma unroll
      for (int s = 0; s < 2; ++s)
        #pragma unroll
        for (int cm = 0; cm < 2; ++cm)
          #pragma unroll
          for (int q = 0; q < 4; ++q)
            #pragma unroll
            for (int p = 0; p < 2; ++p) {
              unsigned u = P[s][cm][q][p];
              m = fmaxf(m, __uint_as_float(u << 16));
              m = fmaxf(m, __uint_as_float(u & 0xffff0000u));
            }
      #pragma unroll
      for (int off = 1; off < 64; off <<= 1) m = fmaxf(m, __shfl_xor(m, off));
      float inv = 1.0f / m;
      #pragma unroll
      for (int s = 0; s < 2; ++s)
        #pragma unroll
        for (int cm = 0; cm < 2; ++cm)
          #pragma unroll
          for (int q = 0; q < 4; ++q)
            #pragma unroll
            for (int p = 0; p < 2; ++p) {
              unsigned u = P[s][cm][q][p];
              P[s][cm][q][p] = cvtpk(__uint_as_float(u << 16) * inv,
                                     __uint_as_float(u & 0xffff0000u) * inv);
            }
      logscale += logf(m);
    }
  }

  // store N_c bf16 row-major [row][col] (state is bf16 — bit-identical info,
  // half the NT traffic; K5 loads A-fragments directly as bf16x8)
  unsigned short* No = (unsigned short*)(NTb + (((size_t)b * 512 + chunk) << 12));
  #pragma unroll
  for (int s = 0; s < 2; ++s)
    #pragma unroll
    for (int cm = 0; cm < 2; ++cm)
      #pragma unroll
      for (int q = 0; q < 4; ++q)
        #pragma unroll
        for (int p = 0; p < 2; ++p) {
          int row = 32 * cm + 8 * q + 4 * hi + 2 * p;
          int col = s * 32 + l31;
          unsigned u = P[s][cm][q][p];
          No[row * 64 + col] = (unsigned short)(u & 0xffffu);
          No[(row + 1) * 64 + col] = (unsigned short)(u >> 16);
        }

  // aux[b][chunk] = sum cmax + chunk logscale
  float cs = (lane < nsteps) ? cmax[(size_t)b * 4096 + t0 + lane] : 0.f;
  #pragma unroll
  for (int off = 1; off < 64; off <<= 1) cs += __shfl_xor(cs, off);
  if (lane == 0) aux[(size_t)b * 512 + chunk] = cs + logscale;
}

// ---------------- K5: merge 16 chunks -> group matrix (32 groups/batch) -----
// r8: grid (32,8) = 256 blocks — fills all CUs (was 128). A-fragments load
// directly from bf16 NT (no f32 load + cvtpk). Rescale every 4th product.
__global__ __launch_bounds__(256) void mmm_merge_kernel(
    const short* __restrict__ NTb, const float* __restrict__ aux,
    float* __restrict__ G2T, float* __restrict__ auxg) {
  int g = blockIdx.x, b = blockIdx.y;
  int tid = threadIdx.x;
  int w = tid >> 6, lane = tid & 63;
  int wi = w >> 1, wj = w & 1;
  int lr = lane & 15, lg = lane >> 4;

  __shared__ __align__(16) short L[2][4096];
  __shared__ float wmax[4];

  for (int idx = tid; idx < 4096; idx += 256) {
    int j = idx >> 6, k = idx & 63;
    L[0][idx ^ ((j & 7) << 3)] = (j == k) ? (short)0x3F80 : (short)0;
  }
  __syncthreads();

  int cbase = b * 512 + g * 16;

  float logscale = 0.f;
  int cur = 0;
  f32x4 acc[2][2];

  bf16x8 apre[2][2];
  {
    const short* Mc = NTb + ((size_t)cbase << 12);
    #pragma unroll
    for (int rt = 0; rt < 2; ++rt)
      #pragma unroll
      for (int kc = 0; kc < 2; ++kc)
        apre[rt][kc] = *(const bf16x8*)&Mc[(wi * 32 + rt * 16 + lr) * 64 + kc * 32 + lg * 8];
  }

  for (int cc = 0; cc < 16; ++cc) {
    bf16x8 acur[2][2];
    #pragma unroll
    for (int rt = 0; rt < 2; ++rt)
      #pragma unroll
      for (int kc = 0; kc < 2; ++kc) acur[rt][kc] = apre[rt][kc];
    if (cc < 15) {
      const short* Mc = NTb + ((size_t)(cbase + cc + 1) << 12);
      #pragma unroll
      for (int rt = 0; rt < 2; ++rt)
        #pragma unroll
        for (int kc = 0; kc < 2; ++kc)
          apre[rt][kc] = *(const bf16x8*)&Mc[(wi * 32 + rt * 16 + lr) * 64 + kc * 32 + lg * 8];
    }

    logscale += aux[cbase + cc];

    bf16x8 bfr[2][2];
    #pragma unroll
    for (int ct = 0; ct < 2; ++ct) {
      int j = wj * 32 + ct * 16 + lr;
      int sw = (j & 7) << 3;
      #pragma unroll
      for (int kc = 0; kc < 2; ++kc)
        bfr[ct][kc] = *(const bf16x8*)&L[cur][(j * 64 + kc * 32 + lg * 8) ^ sw];
    }

    #pragma unroll
    for (int rt = 0; rt < 2; ++rt)
      #pragma unroll
      for (int ct = 0; ct < 2; ++ct) {
        f32x4 c = {0.f, 0.f, 0.f, 0.f};
        c = mfma16(acur[rt][0], bfr[ct][0], c);
        c = mfma16(acur[rt][1], bfr[ct][1], c);
        acc[rt][ct] = c;
      }

    if ((cc & 3) == 3) {  // rescale every 4th product
      float m = 0.f;
      #pragma unroll
      for (int rt = 0; rt < 2; ++rt)
        #pragma unroll
        for (int ct = 0; ct < 2; ++ct)
          #pragma unroll
          for (int r = 0; r < 4; ++r) m = fmaxf(m, acc[rt][ct][r]);
      #pragma unroll
      for (int off = 1; off < 64; off <<= 1) m = fmaxf(m, __shfl_xor(m, off));
      if (lane == 0) wmax[w] = m;
      __syncthreads();
      m = fmaxf(fmaxf(wmax[0], wmax[1]), fmaxf(wmax[2], wmax[3]));
      float inv = 1.0f / m;
      #pragma unroll
      for (int rt = 0; rt < 2; ++rt)
        #pragma unroll
        for (int ct = 0; ct < 2; ++ct) acc[rt][ct] *= inv;
      logscale += logf(m);
    }

    int nxt = cur ^ 1;
    unsigned* L32 = (unsigned*)&L[nxt][0];
    #pragma unroll
    for (int rt = 0; rt < 2; ++rt)
      #pragma unroll
      for (int ct = 0; ct < 2; ++ct) {
        int row0 = wi * 32 + rt * 16 + lg * 4;   // 4-aligned
        int col = wj * 32 + ct * 16 + lr;
        int sidx = (col * 64 + row0) ^ ((col & 7) << 3);  // XOR hits bits>=3 only
        L32[(sidx >> 1) + 0] = cvtpk(acc[rt][ct][0], acc[rt][ct][1]);
        L32[(sidx >> 1) + 1] = cvtpk(acc[rt][ct][2], acc[rt][ct][3]);
      }
    __syncthreads();
    cur = nxt;
  }

  float* Mo = G2T + (((size_t)b * 32 + g) << 12);
  #pragma unroll
  for (int rt = 0; rt < 2; ++rt)
    #pragma unroll
    for (int ct = 0; ct < 2; ++ct)
      #pragma unroll
      for (int r = 0; r < 4; ++r) {
        int row = wi * 32 + rt * 16 + lg * 4 + r;
        int col = wj * 32 + ct * 16 + lr;
        Mo[row * 64 + col] = acc[rt][ct][r];
      }

  if (w == 0 && lane == 0) auxg[b * 32 + g] = logscale;
}

// ---------------- K6: final combine (32 group matrices per batch) -----------
__global__ __launch_bounds__(64) void mmm_combine_kernel(
    const float* __restrict__ pi_logits, const float* __restrict__ ehat,
    const float* __restrict__ cmax, const float* __restrict__ G2T,
    const float* __restrict__ auxg, float* __restrict__ out) {
  int b = blockIdx.x, lane = threadIdx.x;
  __shared__ __align__(16) float alds[64];

  float pv = pi_logits[lane];
  float mx = pv;
  #pragma unroll
  for (int off = 1; off < 64; off <<= 1) mx = fmaxf(mx, __shfl_xor(mx, off));
  float pe = expf(pv - mx);
  float ps = pe;
  #pragma unroll
  for (int off = 1; off < 64; off <<= 1) ps += __shfl_xor(ps, off);

  float a = (pe / ps) * ehat[(size_t)b * 4096 * 64 + lane];
  double logtot = (double)cmax[(size_t)b * 4096];
  alds[lane] = a;
  __builtin_amdgcn_wave_barrier();

  const float* Mb = G2T + (((size_t)b * 32) << 12) + lane * 64;
  f32x4 mc[16], mn[16];
  #pragma unroll
  for (int i = 0; i < 16; ++i) mc[i] = *(const f32x4*)&Mb[i * 4];

  for (int g = 0; g < 32; ++g) {
    if (g < 31) {
      const float* Mn = Mb + ((size_t)(g + 1) << 12);
      #pragma unroll
      for (int i = 0; i < 16; ++i) mn[i] = *(const f32x4*)&Mn[i * 4];
    }
    f32x4 a4 = {0.f, 0.f, 0.f, 0.f};
    #pragma unroll
    for (int i = 0; i < 16; ++i) {
      f32x4 av = *(const f32x4*)&alds[i * 4];
      a4 += mc[i] * av;
    }
    float acc = (a4[0] + a4[1]) + (a4[2] + a4[3]);
    float s = acc;
    #pragma unroll
    for (int off = 1; off < 64; off <<= 1) s += __shfl_xor(s, off);
    logtot += (double)(auxg[b * 32 + g] + logf(s));
    float an = acc / s;
    __builtin_amdgcn_wave_barrier();
    alds[lane] = an;
    __builtin_amdgcn_wave_barrier();
    #pragma unroll
    for (int i = 0; i < 16; ++i) mc[i] = mn[i];
  }
  if (lane == 0) out[b] = (float)logtot;
}

extern "C" void kernel_launch(void* const* d_in, const int* in_sizes, int n_in,
                              void* d_out, int out_size, void* d_ws, size_t ws_size,
                              hipStream_t stream) {
  const float* X      = (const float*)d_in[0];
  const float* pi_l   = (const float*)d_in[1];
  const float* tr_l   = (const float*)d_in[2];
  const float* wl     = (const float*)d_in[3];
  const float* means  = (const float*)d_in[4];
  const float* lvs    = (const float*)d_in[5];
  float* out = (float*)d_out;

  float* ws = (float*)d_ws;
  short* Gt      = (short*)ws;                 // 131072 shorts = 65536 f32
  float* const_c = ws + 65536;                 // 512
  short* WTbf    = (short*)(ws + 66048);       // 4096 shorts = 2048 f32
  float* cmaxp   = ws + 68608;                 // 32768
  float* ehat    = ws + 101376;                // 2097152
  short* XeP     = (short*)(ws + 2198528);     // 16 MB
  short* NTb     = (short*)(ws + 2198528);     // aliases XeP; 16.7M shorts = 33.5 MB
  float* aux     = ws + 10587136;              // 4096 (512 chunks x 8 b)
  float* G2T     = ws + 10591232;              // 1048576 (8 b x 32 g x 4096)
  float* auxg    = ws + 11639808;              // 256

  mmm_prep_fused<<<832, 256, 0, stream>>>(tr_l, means, lvs, wl, X,
                                          WTbf, Gt, const_c, XeP);
  mmm_emis_kernel<<<256, 512, 0, stream>>>(Gt, XeP, const_c, ehat, cmaxp);
  mmm_chunk_kernel<<<dim3(512, 8), 64, 0, stream>>>(WTbf, ehat, cmaxp, NTb, aux);
  mmm_merge_kernel<<<dim3(32, 8), 256, 0, stream>>>(NTb, aux, G2T, auxg);
  mmm_combine_kernel<<<8, 64, 0, stream>>>(pi_l, ehat, cmaxp, G2T, auxg, out);
}

// Round 9
// 115.089 us; speedup vs baseline: 1.1371x; 1.1371x over previous
//
#include <hip/hip_runtime.h>
#include <hip/hip_bf16.h>
#include <math.h>

#define LOG2PI_F 1.8378770664093453f

typedef __attribute__((ext_vector_type(8))) short bf16x8;
typedef __attribute__((ext_vector_type(4))) float f32x4;
typedef __attribute__((ext_vector_type(16))) float f32x16;

static __device__ inline short f2bf(float x) {
  __hip_bfloat16 h = __float2bfloat16(x);
  return *reinterpret_cast<short*>(&h);
}
// HW packed f32->bf16 (RNE). Session A/B (r1 vs r2) showed >= sw pack here.
static __device__ inline unsigned cvtpk(float lo, float hi) {
  unsigned r;
  asm("v_cvt_pk_bf16_f32 %0, %1, %2" : "=v"(r) : "v"(lo), "v"(hi));
  return r;
}
static __device__ inline f32x4 mfma16(bf16x8 a, bf16x8 b, f32x4 c) {
  return __builtin_amdgcn_mfma_f32_16x16x32_bf16(a, b, c, 0, 0, 0);
}
static __device__ inline f32x16 mfma32(bf16x8 a, bf16x8 b, f32x16 c) {
  return __builtin_amdgcn_mfma_f32_32x32x16_bf16(a, b, c, 0, 0, 0);
}

// ---------------- K012: fused prep (WTbf + Gt/const_c + XeP) ----------------
__global__ __launch_bounds__(256) void mmm_prep_fused(
    const float* __restrict__ tl, const float* __restrict__ means,
    const float* __restrict__ log_vars, const float* __restrict__ weight_logits,
    const float* __restrict__ X,
    short* __restrict__ WTbf, short* __restrict__ Gt,
    float* __restrict__ const_c, short* __restrict__ XeP) {
  __shared__ float red[4];
  int bid = blockIdx.x;
  int tid = threadIdx.x;

  if (bid < 64) {               // ---- K0 ----
    if (tid < 64) {
      int r = bid, lane = tid;
      float v = tl[r * 64 + lane];
      float mx = v;
      #pragma unroll
      for (int off = 1; off < 64; off <<= 1) mx = fmaxf(mx, __shfl_xor(mx, off));
      float e = expf(v - mx);
      float s = e;
      #pragma unroll
      for (int off = 1; off < 64; off <<= 1) s += __shfl_xor(s, off);
      WTbf[lane * 64 + r] = f2bf(e / s);
    }
    return;
  }

  if (bid < 320) {              // ---- K1 (2 sm per block) ----
    int h = tid >> 7, d = tid & 127;
    int sm = (bid - 64) * 2 + h;
    int s = sm >> 3, m = sm & 7;
    float lv = log_vars[sm * 128 + d];
    float iv = expf(-lv);
    float mu = means[sm * 128 + d];
    float miv = mu * iv;
    Gt[sm * 256 + d] = f2bf(miv);
    Gt[sm * 256 + 128 + d] = f2bf(-0.5f * iv);
    float v = mu * miv + lv;
    #pragma unroll
    for (int off = 1; off < 64; off <<= 1) v += __shfl_xor(v, off);
    if ((tid & 63) == 0) red[tid >> 6] = v;
    __syncthreads();
    if (d == 0) {
      float tot = red[2 * h] + red[2 * h + 1];
      float wl[8];
      float mx = -3.4e38f;
      #pragma unroll
      for (int j = 0; j < 8; ++j) { wl[j] = weight_logits[s * 8 + j]; mx = fmaxf(mx, wl[j]); }
      float sum = 0.f;
      #pragma unroll
      for (int j = 0; j < 8; ++j) sum += expf(wl[j] - mx);
      float lmw = wl[m] - mx - logf(sum);
      const_c[sm] = -0.5f * (tot + 128.0f * LOG2PI_F) + lmw;
    }
    return;
  }

  // ---- K2 ----
  int kbid = bid - 320;
  int q = kbid >> 7;
  int bt = ((kbid & 127) << 8) + tid;
  const float4* src = (const float4*)(X + (size_t)bt * 128 + q * 32);
  float xv[32];
  #pragma unroll
  for (int i = 0; i < 8; ++i) {
    float4 v = src[i];
    xv[4 * i] = v.x; xv[4 * i + 1] = v.y; xv[4 * i + 2] = v.z; xv[4 * i + 3] = v.w;
  }
  size_t base1 = ((size_t)q * 32768 + bt) * 32;
  size_t base2 = ((size_t)(q + 4) * 32768 + bt) * 32;
  int bx = bt & 3;
  #pragma unroll
  for (int g = 0; g < 4; ++g) {
    unsigned w1[4], w2[4];
    #pragma unroll
    for (int j = 0; j < 4; ++j) {
      float a = xv[g * 8 + 2 * j], c = xv[g * 8 + 2 * j + 1];
      w1[j] = cvtpk(a, c);
      w2[j] = cvtpk(a * a, c * c);
    }
    int gs = (g ^ bx) * 8;
    *(uint4*)&XeP[base1 + gs] = *(uint4*)w1;
    *(uint4*)&XeP[base2 + gs] = *(uint4*)w2;
  }
}

// ---------------- K3: MFMA emission GEMM, C[sm=512][bt=64-tile] ------------
__global__ __launch_bounds__(512) void mmm_emis_kernel(
    const short* __restrict__ Gt, const short* __restrict__ XeP,
    const float* __restrict__ const_c,
    float* __restrict__ ehat, float* __restrict__ cmax) {
  __shared__ __align__(16) short Bt[16384];  // 32 KB
  __shared__ __align__(16) float ccs[512];
  __shared__ float wavemax[8][64];
  __shared__ float colmax[64];
  int tid = threadIdx.x;
  int w = tid >> 6, lane = tid & 63, lr = lane & 15, lg = lane >> 4;

  ccs[tid] = const_c[tid];

  bf16x8 gf[4][8];
  #pragma unroll
  for (int rt = 0; rt < 4; ++rt) {
    int row = w * 64 + rt * 16 + lr;
    #pragma unroll
    for (int kc = 0; kc < 8; ++kc)
      gf[rt][kc] = *(const bf16x8*)&Gt[row * 256 + kc * 32 + lg * 8];
  }

  uint4 sreg[4];
  {
    size_t bt0 = (size_t)blockIdx.x * 64;
    #pragma unroll
    for (int r = 0; r < 4; ++r) {
      int ofs = r * 8192 + tid * 16;
      int kb2 = ofs >> 12, rem = ofs & 4095;
      sreg[r] = *(const uint4*)((const char*)XeP + ((size_t)kb2 * 32768 + bt0) * 64 + rem);
    }
  }

  for (int it = 0; it < 2; ++it) {
    int bt0 = (blockIdx.x + it * 256) * 64;
    __syncthreads();
    #pragma unroll
    for (int r = 0; r < 4; ++r)
      *(uint4*)((char*)Bt + r * 8192 + tid * 16) = sreg[r];
    __syncthreads();
    if (it == 0) {
      size_t bt0n = ((size_t)blockIdx.x + 256) * 64;
      #pragma unroll
      for (int r = 0; r < 4; ++r) {
        int ofs = r * 8192 + tid * 16;
        int kb2 = ofs >> 12, rem = ofs & 4095;
        sreg[r] = *(const uint4*)((const char*)XeP + ((size_t)kb2 * 32768 + bt0n) * 64 + rem);
      }
    }

    f32x4 acc[4][4];
    #pragma unroll
    for (int rt = 0; rt < 4; ++rt)
      #pragma unroll
      for (int ct = 0; ct < 4; ++ct)
        acc[rt][ct] = (f32x4){0.f, 0.f, 0.f, 0.f};

    #pragma unroll
    for (int kc = 0; kc < 8; ++kc) {
      bf16x8 bfr[4];
      #pragma unroll
      for (int ct = 0; ct < 4; ++ct) {
        int btL = ct * 16 + lr;
        bfr[ct] = *(const bf16x8*)&Bt[kc * 2048 + btL * 32 + ((lg ^ (btL & 3)) * 8)];
      }
      #pragma unroll
      for (int rt = 0; rt < 4; ++rt)
        #pragma unroll
        for (int ct = 0; ct < 4; ++ct)
          acc[rt][ct] = mfma16(gf[rt][kc], bfr[ct], acc[rt][ct]);
    }

    float lse[4][4];
    #pragma unroll
    for (int rt = 0; rt < 4; ++rt) {
      f32x4 cc = *(f32x4*)&ccs[w * 64 + rt * 16 + lg * 4];
      #pragma unroll
      for (int ct = 0; ct < 4; ++ct) {
        f32x4 v = acc[rt][ct] + cc;
        float mx = fmaxf(fmaxf(v[0], v[1]), fmaxf(v[2], v[3]));
        mx = fmaxf(mx, __shfl_xor(mx, 16));
        float sum = expf(v[0] - mx) + expf(v[1] - mx) + expf(v[2] - mx) + expf(v[3] - mx);
        sum += __shfl_xor(sum, 16);
        lse[rt][ct] = mx + logf(sum);
      }
    }
    #pragma unroll
    for (int ct = 0; ct < 4; ++ct) {
      float cm = fmaxf(fmaxf(lse[0][ct], lse[1][ct]), fmaxf(lse[2][ct], lse[3][ct]));
      cm = fmaxf(cm, __shfl_xor(cm, 32));
      if (lg == 0) wavemax[w][ct * 16 + lr] = cm;
    }
    __syncthreads();
    if (w == 0) {
      float cm = wavemax[0][lane];
      #pragma unroll
      for (int ww = 1; ww < 8; ++ww) cm = fmaxf(cm, wavemax[ww][lane]);
      colmax[lane] = cm;
      cmax[(size_t)bt0 + lane] = cm;
    }
    __syncthreads();
    #pragma unroll
    for (int ct = 0; ct < 4; ++ct) {
      float cm = colmax[ct * 16 + lr];
      #pragma unroll
      for (int rt = 0; rt < 4; ++rt) {
        float v = expf(lse[rt][ct] - cm);
        if (!(lg & 1))
          ehat[((size_t)bt0 + ct * 16 + lr) * 64 + (w * 8 + rt * 2 + (lg >> 1))] = v;
      }
    }
  }
}

// ---------------- K4: per-chunk product, single fat wave, 8-step chunks -----
// r9: r8 minus the launch_bounds min-waves hint. r8's (64,4) capped VGPRs at
// 64 -> spilled the ~84-reg live state to scratch (FETCH 4->25 MB, WRITE
// 33->99 MB, K4 50us). Default cap lets the allocator use ~84-100 regs
// (r2's 84 fits 5 waves/SIMD); the 4096-block grid then supplies the
// 4 waves/SIMD residency this latency-bound loop needs, spill-free.
__global__ __launch_bounds__(64) void mmm_chunk_kernel(
    const short* __restrict__ WTbf, const float* __restrict__ ehat,
    const float* __restrict__ cmax, short* __restrict__ NTb,
    float* __restrict__ aux) {
  __shared__ __align__(16) float elds[512];  // 8 steps x 64 rows
  int chunk = blockIdx.x, b = blockIdx.y;    // chunk in [0,512)
  int lane = threadIdx.x;
  int l31 = lane & 31, hi = lane >> 5;

  int t0 = (chunk == 0) ? 1 : chunk * 8;
  int nsteps = (chunk == 0) ? 7 : 8;
  const float* eb = ehat + (size_t)b * 4096 * 64;

  // stage e-slice (8 rows x 64 = 2KB, coalesced)
  {
    const float* esrc = eb + (size_t)t0 * 64;
    #pragma unroll
    for (int r = 0; r < 2; ++r)
      *(f32x4*)&elds[r * 256 + lane * 4] = *(const f32x4*)&esrc[r * 256 + lane * 4];
  }

  // A = W^T: af[wi][kb], row = wi*32+l31, k = kb*16 + hi*8 + j
  bf16x8 af[2][4];
  #pragma unroll
  for (int wi = 0; wi < 2; ++wi)
    #pragma unroll
    for (int kb = 0; kb < 4; ++kb)
      af[wi][kb] = *(const bf16x8*)&WTbf[(wi * 32 + l31) * 64 + kb * 16 + hi * 8];

  // packed state: P[s][cm][q][p] = bf16 rows {32cm+8q+4hi+2p, +1} at col s*32+l31
  unsigned P[2][2][4][2];
  #pragma unroll
  for (int s = 0; s < 2; ++s) {
    int col = s * 32 + l31;
    #pragma unroll
    for (int cm = 0; cm < 2; ++cm)
      #pragma unroll
      for (int q = 0; q < 4; ++q)
        #pragma unroll
        for (int p = 0; p < 2; ++p) {
          int row = 32 * cm + 8 * q + 4 * hi + 2 * p;
          unsigned lo = (row == col) ? 0x3F80u : 0u;       // bf16(1.0)
          unsigned h16 = (row + 1 == col) ? 0x3F80u : 0u;
          P[s][cm][q][p] = lo | (h16 << 16);
        }
  }

  __syncthreads();  // e-slice visible wave-wide

  float logscale = 0.f;

  for (int it = 0; it < nsteps; ++it) {
    f32x4 ev[2][4];
    #pragma unroll
    for (int cm = 0; cm < 2; ++cm)
      #pragma unroll
      for (int q = 0; q < 4; ++q)
        ev[cm][q] = *(const f32x4*)&elds[it * 64 + cm * 32 + q * 8 + hi * 4];

    __builtin_amdgcn_s_setprio(1);
    #pragma unroll
    for (int s = 0; s < 2; ++s) {
      // B[kb]: k = kb*16 + 8*hi + j; one permlane32_swap per (quad-pair, p)
      bf16x8 B[4];
      #pragma unroll
      for (int kb = 0; kb < 4; ++kb) {
        int cm = kb >> 1, kbl = kb & 1;
        int4 wrd;
        #pragma unroll
        for (int p = 0; p < 2; ++p) {
          unsigned avv = P[s][cm][2 * kbl + 1][p];
          unsigned bvv = P[s][cm][2 * kbl][p];
          asm("v_permlane32_swap_b32 %0, %1" : "+v"(avv), "+v"(bvv));
          if (p == 0) { wrd.x = (int)bvv; wrd.z = (int)avv; }
          else        { wrd.y = (int)bvv; wrd.w = (int)avv; }
        }
        B[kb] = *(bf16x8*)&wrd;
      }

      f32x16 d0, d1;
      #pragma unroll
      for (int r = 0; r < 16; ++r) { d0[r] = 0.f; d1[r] = 0.f; }
      #pragma unroll
      for (int kb = 0; kb < 4; ++kb) {
        d0 = mfma32(af[0][kb], B[kb], d0);
        d1 = mfma32(af[1][kb], B[kb], d1);
      }

      // P = pack(d * e): reg 4q+s_ -> row 32cm+8q+4hi+s_
      #pragma unroll
      for (int q = 0; q < 4; ++q)
        #pragma unroll
        for (int p = 0; p < 2; ++p) {
          P[s][0][q][p] = cvtpk(d0[4 * q + 2 * p] * ev[0][q][2 * p],
                                d0[4 * q + 2 * p + 1] * ev[0][q][2 * p + 1]);
          P[s][1][q][p] = cvtpk(d1[4 * q + 2 * p] * ev[1][q][2 * p],
                                d1[4 * q + 2 * p + 1] * ev[1][q][2 * p + 1]);
        }
    }
    __builtin_amdgcn_s_setprio(0);

    if ((it & 7) == 7) {  // end-of-chunk rescale (same 8-step cadence as before)
      float m = 0.f;
      #pragma unroll
      for (int s = 0; s < 2; ++s)
        #pragma unroll
        for (int cm = 0; cm < 2; ++cm)
          #pragma unroll
          for (int q = 0; q < 4; ++q)
            #pragma unroll
            for (int p = 0; p < 2; ++p) {
              unsigned u = P[s][cm][q][p];
              m = fmaxf(m, __uint_as_float(u << 16));
              m = fmaxf(m, __uint_as_float(u & 0xffff0000u));
            }
      #pragma unroll
      for (int off = 1; off < 64; off <<= 1) m = fmaxf(m, __shfl_xor(m, off));
      float inv = 1.0f / m;
      #pragma unroll
      for (int s = 0; s < 2; ++s)
        #pragma unroll
        for (int cm = 0; cm < 2; ++cm)
          #pragma unroll
          for (int q = 0; q < 4; ++q)
            #pragma unroll
            for (int p = 0; p < 2; ++p) {
              unsigned u = P[s][cm][q][p];
              P[s][cm][q][p] = cvtpk(__uint_as_float(u << 16) * inv,
                                     __uint_as_float(u & 0xffff0000u) * inv);
            }
      logscale += logf(m);
    }
  }

  // store N_c bf16 row-major [row][col]
  unsigned short* No = (unsigned short*)(NTb + (((size_t)b * 512 + chunk) << 12));
  #pragma unroll
  for (int s = 0; s < 2; ++s)
    #pragma unroll
    for (int cm = 0; cm < 2; ++cm)
      #pragma unroll
      for (int q = 0; q < 4; ++q)
        #pragma unroll
        for (int p = 0; p < 2; ++p) {
          int row = 32 * cm + 8 * q + 4 * hi + 2 * p;
          int col = s * 32 + l31;
          unsigned u = P[s][cm][q][p];
          No[row * 64 + col] = (unsigned short)(u & 0xffffu);
          No[(row + 1) * 64 + col] = (unsigned short)(u >> 16);
        }

  // aux[b][chunk] = sum cmax + chunk logscale
  float cs = (lane < nsteps) ? cmax[(size_t)b * 4096 + t0 + lane] : 0.f;
  #pragma unroll
  for (int off = 1; off < 64; off <<= 1) cs += __shfl_xor(cs, off);
  if (lane == 0) aux[(size_t)b * 512 + chunk] = cs + logscale;
}

// ---------------- K5: merge 16 chunks -> group matrix (32 groups/batch) -----
__global__ __launch_bounds__(256) void mmm_merge_kernel(
    const short* __restrict__ NTb, const float* __restrict__ aux,
    float* __restrict__ G2T, float* __restrict__ auxg) {
  int g = blockIdx.x, b = blockIdx.y;
  int tid = threadIdx.x;
  int w = tid >> 6, lane = tid & 63;
  int wi = w >> 1, wj = w & 1;
  int lr = lane & 15, lg = lane >> 4;

  __shared__ __align__(16) short L[2][4096];
  __shared__ float wmax[4];

  for (int idx = tid; idx < 4096; idx += 256) {
    int j = idx >> 6, k = idx & 63;
    L[0][idx ^ ((j & 7) << 3)] = (j == k) ? (short)0x3F80 : (short)0;
  }
  __syncthreads();

  int cbase = b * 512 + g * 16;

  float logscale = 0.f;
  int cur = 0;
  f32x4 acc[2][2];

  bf16x8 apre[2][2];
  {
    const short* Mc = NTb + ((size_t)cbase << 12);
    #pragma unroll
    for (int rt = 0; rt < 2; ++rt)
      #pragma unroll
      for (int kc = 0; kc < 2; ++kc)
        apre[rt][kc] = *(const bf16x8*)&Mc[(wi * 32 + rt * 16 + lr) * 64 + kc * 32 + lg * 8];
  }

  for (int cc = 0; cc < 16; ++cc) {
    bf16x8 acur[2][2];
    #pragma unroll
    for (int rt = 0; rt < 2; ++rt)
      #pragma unroll
      for (int kc = 0; kc < 2; ++kc) acur[rt][kc] = apre[rt][kc];
    if (cc < 15) {
      const short* Mc = NTb + ((size_t)(cbase + cc + 1) << 12);
      #pragma unroll
      for (int rt = 0; rt < 2; ++rt)
        #pragma unroll
        for (int kc = 0; kc < 2; ++kc)
          apre[rt][kc] = *(const bf16x8*)&Mc[(wi * 32 + rt * 16 + lr) * 64 + kc * 32 + lg * 8];
    }

    logscale += aux[cbase + cc];

    bf16x8 bfr[2][2];
    #pragma unroll
    for (int ct = 0; ct < 2; ++ct) {
      int j = wj * 32 + ct * 16 + lr;
      int sw = (j & 7) << 3;
      #pragma unroll
      for (int kc = 0; kc < 2; ++kc)
        bfr[ct][kc] = *(const bf16x8*)&L[cur][(j * 64 + kc * 32 + lg * 8) ^ sw];
    }

    #pragma unroll
    for (int rt = 0; rt < 2; ++rt)
      #pragma unroll
      for (int ct = 0; ct < 2; ++ct) {
        f32x4 c = {0.f, 0.f, 0.f, 0.f};
        c = mfma16(acur[rt][0], bfr[ct][0], c);
        c = mfma16(acur[rt][1], bfr[ct][1], c);
        acc[rt][ct] = c;
      }

    if ((cc & 3) == 3) {  // rescale every 4th product
      float m = 0.f;
      #pragma unroll
      for (int rt = 0; rt < 2; ++rt)
        #pragma unroll
        for (int ct = 0; ct < 2; ++ct)
          #pragma unroll
          for (int r = 0; r < 4; ++r) m = fmaxf(m, acc[rt][ct][r]);
      #pragma unroll
      for (int off = 1; off < 64; off <<= 1) m = fmaxf(m, __shfl_xor(m, off));
      if (lane == 0) wmax[w] = m;
      __syncthreads();
      m = fmaxf(fmaxf(wmax[0], wmax[1]), fmaxf(wmax[2], wmax[3]));
      float inv = 1.0f / m;
      #pragma unroll
      for (int rt = 0; rt < 2; ++rt)
        #pragma unroll
        for (int ct = 0; ct < 2; ++ct) acc[rt][ct] *= inv;
      logscale += logf(m);
    }

    int nxt = cur ^ 1;
    unsigned* L32 = (unsigned*)&L[nxt][0];
    #pragma unroll
    for (int rt = 0; rt < 2; ++rt)
      #pragma unroll
      for (int ct = 0; ct < 2; ++ct) {
        int row0 = wi * 32 + rt * 16 + lg * 4;   // 4-aligned
        int col = wj * 32 + ct * 16 + lr;
        int sidx = (col * 64 + row0) ^ ((col & 7) << 3);  // XOR hits bits>=3 only
        L32[(sidx >> 1) + 0] = cvtpk(acc[rt][ct][0], acc[rt][ct][1]);
        L32[(sidx >> 1) + 1] = cvtpk(acc[rt][ct][2], acc[rt][ct][3]);
      }
    __syncthreads();
    cur = nxt;
  }

  float* Mo = G2T + (((size_t)b * 32 + g) << 12);
  #pragma unroll
  for (int rt = 0; rt < 2; ++rt)
    #pragma unroll
    for (int ct = 0; ct < 2; ++ct)
      #pragma unroll
      for (int r = 0; r < 4; ++r) {
        int row = wi * 32 + rt * 16 + lg * 4 + r;
        int col = wj * 32 + ct * 16 + lr;
        Mo[row * 64 + col] = acc[rt][ct][r];
      }

  if (w == 0 && lane == 0) auxg[b * 32 + g] = logscale;
}

// ---------------- K6: final combine (32 group matrices per batch) -----------
__global__ __launch_bounds__(64) void mmm_combine_kernel(
    const float* __restrict__ pi_logits, const float* __restrict__ ehat,
    const float* __restrict__ cmax, const float* __restrict__ G2T,
    const float* __restrict__ auxg, float* __restrict__ out) {
  int b = blockIdx.x, lane = threadIdx.x;
  __shared__ __align__(16) float alds[64];

  float pv = pi_logits[lane];
  float mx = pv;
  #pragma unroll
  for (int off = 1; off < 64; off <<= 1) mx = fmaxf(mx, __shfl_xor(mx, off));
  float pe = expf(pv - mx);
  float ps = pe;
  #pragma unroll
  for (int off = 1; off < 64; off <<= 1) ps += __shfl_xor(ps, off);

  float a = (pe / ps) * ehat[(size_t)b * 4096 * 64 + lane];
  double logtot = (double)cmax[(size_t)b * 4096];
  alds[lane] = a;
  __builtin_amdgcn_wave_barrier();

  const float* Mb = G2T + (((size_t)b * 32) << 12) + lane * 64;
  f32x4 mc[16], mn[16];
  #pragma unroll
  for (int i = 0; i < 16; ++i) mc[i] = *(const f32x4*)&Mb[i * 4];

  for (int g = 0; g < 32; ++g) {
    if (g < 31) {
      const float* Mn = Mb + ((size_t)(g + 1) << 12);
      #pragma unroll
      for (int i = 0; i < 16; ++i) mn[i] = *(const f32x4*)&Mn[i * 4];
    }
    f32x4 a4 = {0.f, 0.f, 0.f, 0.f};
    #pragma unroll
    for (int i = 0; i < 16; ++i) {
      f32x4 av = *(const f32x4*)&alds[i * 4];
      a4 += mc[i] * av;
    }
    float acc = (a4[0] + a4[1]) + (a4[2] + a4[3]);
    float s = acc;
    #pragma unroll
    for (int off = 1; off < 64; off <<= 1) s += __shfl_xor(s, off);
    logtot += (double)(auxg[b * 32 + g] + logf(s));
    float an = acc / s;
    __builtin_amdgcn_wave_barrier();
    alds[lane] = an;
    __builtin_amdgcn_wave_barrier();
    #pragma unroll
    for (int i = 0; i < 16; ++i) mc[i] = mn[i];
  }
  if (lane == 0) out[b] = (float)logtot;
}

extern "C" void kernel_launch(void* const* d_in, const int* in_sizes, int n_in,
                              void* d_out, int out_size, void* d_ws, size_t ws_size,
                              hipStream_t stream) {
  const float* X      = (const float*)d_in[0];
  const float* pi_l   = (const float*)d_in[1];
  const float* tr_l   = (const float*)d_in[2];
  const float* wl     = (const float*)d_in[3];
  const float* means  = (const float*)d_in[4];
  const float* lvs    = (const float*)d_in[5];
  float* out = (float*)d_out;

  float* ws = (float*)d_ws;
  short* Gt      = (short*)ws;                 // 131072 shorts = 65536 f32
  float* const_c = ws + 65536;                 // 512
  short* WTbf    = (short*)(ws + 66048);       // 4096 shorts = 2048 f32
  float* cmaxp   = ws + 68608;                 // 32768
  float* ehat    = ws + 101376;                // 2097152
  short* XeP     = (short*)(ws + 2198528);     // 16 MB
  short* NTb     = (short*)(ws + 2198528);     // aliases XeP; 16.7M shorts = 33.5 MB
  float* aux     = ws + 10587136;              // 4096 (512 chunks x 8 b)
  float* G2T     = ws + 10591232;              // 1048576 (8 b x 32 g x 4096)
  float* auxg    = ws + 11639808;              // 256

  mmm_prep_fused<<<832, 256, 0, stream>>>(tr_l, means, lvs, wl, X,
                                          WTbf, Gt, const_c, XeP);
  mmm_emis_kernel<<<256, 512, 0, stream>>>(Gt, XeP, const_c, ehat, cmaxp);
  mmm_chunk_kernel<<<dim3(512, 8), 64, 0, stream>>>(WTbf, ehat, cmaxp, NTb, aux);
  mmm_merge_kernel<<<dim3(32, 8), 256, 0, stream>>>(NTb, aux, G2T, auxg);
  mmm_combine_kernel<<<8, 64, 0, stream>>>(pi_l, ehat, cmaxp, G2T, auxg, out);
}

// Round 10
// 113.717 us; speedup vs baseline: 1.1508x; 1.0121x over previous
//
#include <hip/hip_runtime.h>
#include <hip/hip_bf16.h>
#include <math.h>

#define LOG2PI_F 1.8378770664093453f

typedef __attribute__((ext_vector_type(8))) short bf16x8;
typedef __attribute__((ext_vector_type(4))) float f32x4;
typedef __attribute__((ext_vector_type(16))) float f32x16;

static __device__ inline short f2bf(float x) {
  __hip_bfloat16 h = __float2bfloat16(x);
  return *reinterpret_cast<short*>(&h);
}
// HW packed f32->bf16 (RNE). Session A/B (r1 vs r2) showed >= sw pack here.
static __device__ inline unsigned cvtpk(float lo, float hi) {
  unsigned r;
  asm("v_cvt_pk_bf16_f32 %0, %1, %2" : "=v"(r) : "v"(lo), "v"(hi));
  return r;
}
static __device__ inline f32x4 mfma16(bf16x8 a, bf16x8 b, f32x4 c) {
  return __builtin_amdgcn_mfma_f32_16x16x32_bf16(a, b, c, 0, 0, 0);
}
static __device__ inline f32x16 mfma32(bf16x8 a, bf16x8 b, f32x16 c) {
  return __builtin_amdgcn_mfma_f32_32x32x16_bf16(a, b, c, 0, 0, 0);
}

// ---------------- K012: fused prep (WTbf + Gt/const_c + XeP) ----------------
__global__ __launch_bounds__(256) void mmm_prep_fused(
    const float* __restrict__ tl, const float* __restrict__ means,
    const float* __restrict__ log_vars, const float* __restrict__ weight_logits,
    const float* __restrict__ X,
    short* __restrict__ WTbf, short* __restrict__ Gt,
    float* __restrict__ const_c, short* __restrict__ XeP) {
  __shared__ float red[4];
  int bid = blockIdx.x;
  int tid = threadIdx.x;

  if (bid < 64) {               // ---- K0 ----
    if (tid < 64) {
      int r = bid, lane = tid;
      float v = tl[r * 64 + lane];
      float mx = v;
      #pragma unroll
      for (int off = 1; off < 64; off <<= 1) mx = fmaxf(mx, __shfl_xor(mx, off));
      float e = expf(v - mx);
      float s = e;
      #pragma unroll
      for (int off = 1; off < 64; off <<= 1) s += __shfl_xor(s, off);
      WTbf[lane * 64 + r] = f2bf(e / s);
    }
    return;
  }

  if (bid < 320) {              // ---- K1 (2 sm per block) ----
    int h = tid >> 7, d = tid & 127;
    int sm = (bid - 64) * 2 + h;
    int s = sm >> 3, m = sm & 7;
    float lv = log_vars[sm * 128 + d];
    float iv = expf(-lv);
    float mu = means[sm * 128 + d];
    float miv = mu * iv;
    Gt[sm * 256 + d] = f2bf(miv);
    Gt[sm * 256 + 128 + d] = f2bf(-0.5f * iv);
    float v = mu * miv + lv;
    #pragma unroll
    for (int off = 1; off < 64; off <<= 1) v += __shfl_xor(v, off);
    if ((tid & 63) == 0) red[tid >> 6] = v;
    __syncthreads();
    if (d == 0) {
      float tot = red[2 * h] + red[2 * h + 1];
      float wl[8];
      float mx = -3.4e38f;
      #pragma unroll
      for (int j = 0; j < 8; ++j) { wl[j] = weight_logits[s * 8 + j]; mx = fmaxf(mx, wl[j]); }
      float sum = 0.f;
      #pragma unroll
      for (int j = 0; j < 8; ++j) sum += expf(wl[j] - mx);
      float lmw = wl[m] - mx - logf(sum);
      const_c[sm] = -0.5f * (tot + 128.0f * LOG2PI_F) + lmw;
    }
    return;
  }

  // ---- K2 ----
  int kbid = bid - 320;
  int q = kbid >> 7;
  int bt = ((kbid & 127) << 8) + tid;
  const float4* src = (const float4*)(X + (size_t)bt * 128 + q * 32);
  float xv[32];
  #pragma unroll
  for (int i = 0; i < 8; ++i) {
    float4 v = src[i];
    xv[4 * i] = v.x; xv[4 * i + 1] = v.y; xv[4 * i + 2] = v.z; xv[4 * i + 3] = v.w;
  }
  size_t base1 = ((size_t)q * 32768 + bt) * 32;
  size_t base2 = ((size_t)(q + 4) * 32768 + bt) * 32;
  int bx = bt & 3;
  #pragma unroll
  for (int g = 0; g < 4; ++g) {
    unsigned w1[4], w2[4];
    #pragma unroll
    for (int j = 0; j < 4; ++j) {
      float a = xv[g * 8 + 2 * j], c = xv[g * 8 + 2 * j + 1];
      w1[j] = cvtpk(a, c);
      w2[j] = cvtpk(a * a, c * c);
    }
    int gs = (g ^ bx) * 8;
    *(uint4*)&XeP[base1 + gs] = *(uint4*)w1;
    *(uint4*)&XeP[base2 + gs] = *(uint4*)w2;
  }
}

// ---------------- K3: MFMA emission GEMM, C[sm=512][bt=64-tile] ------------
__global__ __launch_bounds__(512) void mmm_emis_kernel(
    const short* __restrict__ Gt, const short* __restrict__ XeP,
    const float* __restrict__ const_c,
    float* __restrict__ ehat, float* __restrict__ cmax) {
  __shared__ __align__(16) short Bt[16384];  // 32 KB
  __shared__ __align__(16) float ccs[512];
  __shared__ float wavemax[8][64];
  __shared__ float colmax[64];
  int tid = threadIdx.x;
  int w = tid >> 6, lane = tid & 63, lr = lane & 15, lg = lane >> 4;

  ccs[tid] = const_c[tid];

  bf16x8 gf[4][8];
  #pragma unroll
  for (int rt = 0; rt < 4; ++rt) {
    int row = w * 64 + rt * 16 + lr;
    #pragma unroll
    for (int kc = 0; kc < 8; ++kc)
      gf[rt][kc] = *(const bf16x8*)&Gt[row * 256 + kc * 32 + lg * 8];
  }

  uint4 sreg[4];
  {
    size_t bt0 = (size_t)blockIdx.x * 64;
    #pragma unroll
    for (int r = 0; r < 4; ++r) {
      int ofs = r * 8192 + tid * 16;
      int kb2 = ofs >> 12, rem = ofs & 4095;
      sreg[r] = *(const uint4*)((const char*)XeP + ((size_t)kb2 * 32768 + bt0) * 64 + rem);
    }
  }

  for (int it = 0; it < 2; ++it) {
    int bt0 = (blockIdx.x + it * 256) * 64;
    __syncthreads();
    #pragma unroll
    for (int r = 0; r < 4; ++r)
      *(uint4*)((char*)Bt + r * 8192 + tid * 16) = sreg[r];
    __syncthreads();
    if (it == 0) {
      size_t bt0n = ((size_t)blockIdx.x + 256) * 64;
      #pragma unroll
      for (int r = 0; r < 4; ++r) {
        int ofs = r * 8192 + tid * 16;
        int kb2 = ofs >> 12, rem = ofs & 4095;
        sreg[r] = *(const uint4*)((const char*)XeP + ((size_t)kb2 * 32768 + bt0n) * 64 + rem);
      }
    }

    f32x4 acc[4][4];
    #pragma unroll
    for (int rt = 0; rt < 4; ++rt)
      #pragma unroll
      for (int ct = 0; ct < 4; ++ct)
        acc[rt][ct] = (f32x4){0.f, 0.f, 0.f, 0.f};

    #pragma unroll
    for (int kc = 0; kc < 8; ++kc) {
      bf16x8 bfr[4];
      #pragma unroll
      for (int ct = 0; ct < 4; ++ct) {
        int btL = ct * 16 + lr;
        bfr[ct] = *(const bf16x8*)&Bt[kc * 2048 + btL * 32 + ((lg ^ (btL & 3)) * 8)];
      }
      #pragma unroll
      for (int rt = 0; rt < 4; ++rt)
        #pragma unroll
        for (int ct = 0; ct < 4; ++ct)
          acc[rt][ct] = mfma16(gf[rt][kc], bfr[ct], acc[rt][ct]);
    }

    float lse[4][4];
    #pragma unroll
    for (int rt = 0; rt < 4; ++rt) {
      f32x4 cc = *(f32x4*)&ccs[w * 64 + rt * 16 + lg * 4];
      #pragma unroll
      for (int ct = 0; ct < 4; ++ct) {
        f32x4 v = acc[rt][ct] + cc;
        float mx = fmaxf(fmaxf(v[0], v[1]), fmaxf(v[2], v[3]));
        mx = fmaxf(mx, __shfl_xor(mx, 16));
        float sum = expf(v[0] - mx) + expf(v[1] - mx) + expf(v[2] - mx) + expf(v[3] - mx);
        sum += __shfl_xor(sum, 16);
        lse[rt][ct] = mx + logf(sum);
      }
    }
    #pragma unroll
    for (int ct = 0; ct < 4; ++ct) {
      float cm = fmaxf(fmaxf(lse[0][ct], lse[1][ct]), fmaxf(lse[2][ct], lse[3][ct]));
      cm = fmaxf(cm, __shfl_xor(cm, 32));
      if (lg == 0) wavemax[w][ct * 16 + lr] = cm;
    }
    __syncthreads();
    if (w == 0) {
      float cm = wavemax[0][lane];
      #pragma unroll
      for (int ww = 1; ww < 8; ++ww) cm = fmaxf(cm, wavemax[ww][lane]);
      colmax[lane] = cm;
      cmax[(size_t)bt0 + lane] = cm;
    }
    __syncthreads();
    #pragma unroll
    for (int ct = 0; ct < 4; ++ct) {
      float cm = colmax[ct * 16 + lr];
      #pragma unroll
      for (int rt = 0; rt < 4; ++rt) {
        float v = expf(lse[rt][ct] - cm);
        if (!(lg & 1))
          ehat[((size_t)bt0 + ct * 16 + lr) * 64 + (w * 8 + rt * 2 + (lg >> 1))] = v;
      }
    }
  }
}

// ---------------- K4: per-chunk product, single fat wave, 16-step chunks ----
// r10: revert to the proven-best r6 geometry (256 chunks x 16 steps; r9
// showed 8-step/4-wave residency is null-to-negative). Only change vs r6:
// NT stored as bf16 (state is bf16 anyway — bit-identical, half traffic,
// lets K5 load A-fragments directly).
__global__ __launch_bounds__(64) void mmm_chunk_kernel(
    const short* __restrict__ WTbf, const float* __restrict__ ehat,
    const float* __restrict__ cmax, short* __restrict__ NTb,
    float* __restrict__ aux) {
  __shared__ __align__(16) float elds[1024];  // 16 steps x 64 rows
  int chunk = blockIdx.x, b = blockIdx.y;     // chunk in [0,256)
  int lane = threadIdx.x;
  int l31 = lane & 31, hi = lane >> 5;

  int t0 = (chunk == 0) ? 1 : chunk * 16;
  int nsteps = (chunk == 0) ? 15 : 16;
  const float* eb = ehat + (size_t)b * 4096 * 64;

  // stage e-slice first (issue-early): rows t0..t0+15 always in-bounds
  {
    const float* esrc = eb + (size_t)t0 * 64;
    #pragma unroll
    for (int r = 0; r < 4; ++r)
      *(f32x4*)&elds[r * 256 + lane * 4] = *(const f32x4*)&esrc[r * 256 + lane * 4];
  }

  // A = W^T: af[wi][kb], row = wi*32+l31, k = kb*16 + hi*8 + j
  bf16x8 af[2][4];
  #pragma unroll
  for (int wi = 0; wi < 2; ++wi)
    #pragma unroll
    for (int kb = 0; kb < 4; ++kb)
      af[wi][kb] = *(const bf16x8*)&WTbf[(wi * 32 + l31) * 64 + kb * 16 + hi * 8];

  // packed state: P[s][cm][q][p] = bf16 rows {32cm+8q+4hi+2p, +1} at col s*32+l31
  unsigned P[2][2][4][2];
  #pragma unroll
  for (int s = 0; s < 2; ++s) {
    int col = s * 32 + l31;
    #pragma unroll
    for (int cm = 0; cm < 2; ++cm)
      #pragma unroll
      for (int q = 0; q < 4; ++q)
        #pragma unroll
        for (int p = 0; p < 2; ++p) {
          int row = 32 * cm + 8 * q + 4 * hi + 2 * p;
          unsigned lo = (row == col) ? 0x3F80u : 0u;       // bf16(1.0)
          unsigned h16 = (row + 1 == col) ? 0x3F80u : 0u;
          P[s][cm][q][p] = lo | (h16 << 16);
        }
  }

  __syncthreads();  // e-slice visible wave-wide

  float logscale = 0.f;
  f32x4 ecur[2][4], enxt[2][4];
  #pragma unroll
  for (int cm = 0; cm < 2; ++cm)
    #pragma unroll
    for (int q = 0; q < 4; ++q)
      ecur[cm][q] = *(const f32x4*)&elds[cm * 32 + q * 8 + hi * 4];

  for (int it = 0; it < nsteps; ++it) {
    if (it + 1 < nsteps) {  // prefetch next step's e from LDS
      #pragma unroll
      for (int cm = 0; cm < 2; ++cm)
        #pragma unroll
        for (int q = 0; q < 4; ++q)
          enxt[cm][q] = *(const f32x4*)&elds[(it + 1) * 64 + cm * 32 + q * 8 + hi * 4];
    }

    __builtin_amdgcn_s_setprio(1);
    #pragma unroll
    for (int s = 0; s < 2; ++s) {
      // B[kb]: k = kb*16 + 8*hi + j; one permlane32_swap per (quad-pair, p)
      bf16x8 B[4];
      #pragma unroll
      for (int kb = 0; kb < 4; ++kb) {
        int cm = kb >> 1, kbl = kb & 1;
        int4 wrd;
        #pragma unroll
        for (int p = 0; p < 2; ++p) {
          unsigned avv = P[s][cm][2 * kbl + 1][p];
          unsigned bvv = P[s][cm][2 * kbl][p];
          asm("v_permlane32_swap_b32 %0, %1" : "+v"(avv), "+v"(bvv));
          if (p == 0) { wrd.x = (int)bvv; wrd.z = (int)avv; }
          else        { wrd.y = (int)bvv; wrd.w = (int)avv; }
        }
        B[kb] = *(bf16x8*)&wrd;
      }

      f32x16 d0, d1;
      #pragma unroll
      for (int r = 0; r < 16; ++r) { d0[r] = 0.f; d1[r] = 0.f; }
      #pragma unroll
      for (int kb = 0; kb < 4; ++kb) {
        d0 = mfma32(af[0][kb], B[kb], d0);
        d1 = mfma32(af[1][kb], B[kb], d1);
      }

      // P = pack(d * e): reg 4q+s_ -> row 32cm+8q+4hi+s_
      #pragma unroll
      for (int q = 0; q < 4; ++q)
        #pragma unroll
        for (int p = 0; p < 2; ++p) {
          P[s][0][q][p] = cvtpk(d0[4 * q + 2 * p] * ecur[0][q][2 * p],
                                d0[4 * q + 2 * p + 1] * ecur[0][q][2 * p + 1]);
          P[s][1][q][p] = cvtpk(d1[4 * q + 2 * p] * ecur[1][q][2 * p],
                                d1[4 * q + 2 * p + 1] * ecur[1][q][2 * p + 1]);
        }
    }
    __builtin_amdgcn_s_setprio(0);

    if ((it & 7) == 7) {  // whole-chunk rescale, applied in place on P
      float m = 0.f;
      #pragma unroll
      for (int s = 0; s < 2; ++s)
        #pragma unroll
        for (int cm = 0; cm < 2; ++cm)
          #pragma unroll
          for (int q = 0; q < 4; ++q)
            #pragma unroll
            for (int p = 0; p < 2; ++p) {
              unsigned u = P[s][cm][q][p];
              m = fmaxf(m, __uint_as_float(u << 16));
              m = fmaxf(m, __uint_as_float(u & 0xffff0000u));
            }
      #pragma unroll
      for (int off = 1; off < 64; off <<= 1) m = fmaxf(m, __shfl_xor(m, off));
      float inv = 1.0f / m;
      #pragma unroll
      for (int s = 0; s < 2; ++s)
        #pragma unroll
        for (int cm = 0; cm < 2; ++cm)
          #pragma unroll
          for (int q = 0; q < 4; ++q)
            #pragma unroll
            for (int p = 0; p < 2; ++p) {
              unsigned u = P[s][cm][q][p];
              P[s][cm][q][p] = cvtpk(__uint_as_float(u << 16) * inv,
                                     __uint_as_float(u & 0xffff0000u) * inv);
            }
      logscale += logf(m);
    }

    #pragma unroll
    for (int cm = 0; cm < 2; ++cm)
      #pragma unroll
      for (int q = 0; q < 4; ++q) ecur[cm][q] = enxt[cm][q];
  }

  // store N_c bf16 row-major [row][col]
  unsigned short* No = (unsigned short*)(NTb + (((size_t)b * 256 + chunk) << 12));
  #pragma unroll
  for (int s = 0; s < 2; ++s)
    #pragma unroll
    for (int cm = 0; cm < 2; ++cm)
      #pragma unroll
      for (int q = 0; q < 4; ++q)
        #pragma unroll
        for (int p = 0; p < 2; ++p) {
          int row = 32 * cm + 8 * q + 4 * hi + 2 * p;
          int col = s * 32 + l31;
          unsigned u = P[s][cm][q][p];
          No[row * 64 + col] = (unsigned short)(u & 0xffffu);
          No[(row + 1) * 64 + col] = (unsigned short)(u >> 16);
        }

  // aux[b][chunk] = sum cmax + chunk logscale
  float cs = (lane < nsteps) ? cmax[(size_t)b * 4096 + t0 + lane] : 0.f;
  #pragma unroll
  for (int off = 1; off < 64; off <<= 1) cs += __shfl_xor(cs, off);
  if (lane == 0) aux[(size_t)b * 256 + chunk] = cs + logscale;
}

// ---------------- K5: merge 8 chunks -> group matrix (32 groups/batch) ------
// r10: grid (32,8) = 256 blocks — full chip (was 128, half idle) AND serial
// depth halved 16->8. A-fragments load directly as bf16. Rescale every 4th
// product (validated r7); final cc=7 rescales, so G2T semantics unchanged.
__global__ __launch_bounds__(256) void mmm_merge_kernel(
    const short* __restrict__ NTb, const float* __restrict__ aux,
    float* __restrict__ G2T, float* __restrict__ auxg) {
  int g = blockIdx.x, b = blockIdx.y;
  int tid = threadIdx.x;
  int w = tid >> 6, lane = tid & 63;
  int wi = w >> 1, wj = w & 1;
  int lr = lane & 15, lg = lane >> 4;

  __shared__ __align__(16) short L[2][4096];
  __shared__ float wmax[4];

  for (int idx = tid; idx < 4096; idx += 256) {
    int j = idx >> 6, k = idx & 63;
    L[0][idx ^ ((j & 7) << 3)] = (j == k) ? (short)0x3F80 : (short)0;
  }
  __syncthreads();

  int cbase = b * 256 + g * 8;

  float logscale = 0.f;
  int cur = 0;
  f32x4 acc[2][2];

  bf16x8 apre[2][2];
  {
    const short* Mc = NTb + ((size_t)cbase << 12);
    #pragma unroll
    for (int rt = 0; rt < 2; ++rt)
      #pragma unroll
      for (int kc = 0; kc < 2; ++kc)
        apre[rt][kc] = *(const bf16x8*)&Mc[(wi * 32 + rt * 16 + lr) * 64 + kc * 32 + lg * 8];
  }

  for (int cc = 0; cc < 8; ++cc) {
    bf16x8 acur[2][2];
    #pragma unroll
    for (int rt = 0; rt < 2; ++rt)
      #pragma unroll
      for (int kc = 0; kc < 2; ++kc) acur[rt][kc] = apre[rt][kc];
    if (cc < 7) {
      const short* Mc = NTb + ((size_t)(cbase + cc + 1) << 12);
      #pragma unroll
      for (int rt = 0; rt < 2; ++rt)
        #pragma unroll
        for (int kc = 0; kc < 2; ++kc)
          apre[rt][kc] = *(const bf16x8*)&Mc[(wi * 32 + rt * 16 + lr) * 64 + kc * 32 + lg * 8];
    }

    logscale += aux[cbase + cc];

    bf16x8 bfr[2][2];
    #pragma unroll
    for (int ct = 0; ct < 2; ++ct) {
      int j = wj * 32 + ct * 16 + lr;
      int sw = (j & 7) << 3;
      #pragma unroll
      for (int kc = 0; kc < 2; ++kc)
        bfr[ct][kc] = *(const bf16x8*)&L[cur][(j * 64 + kc * 32 + lg * 8) ^ sw];
    }

    #pragma unroll
    for (int rt = 0; rt < 2; ++rt)
      #pragma unroll
      for (int ct = 0; ct < 2; ++ct) {
        f32x4 c = {0.f, 0.f, 0.f, 0.f};
        c = mfma16(acur[rt][0], bfr[ct][0], c);
        c = mfma16(acur[rt][1], bfr[ct][1], c);
        acc[rt][ct] = c;
      }

    if ((cc & 3) == 3) {  // rescale every 4th product (cc=3,7)
      float m = 0.f;
      #pragma unroll
      for (int rt = 0; rt < 2; ++rt)
        #pragma unroll
        for (int ct = 0; ct < 2; ++ct)
          #pragma unroll
          for (int r = 0; r < 4; ++r) m = fmaxf(m, acc[rt][ct][r]);
      #pragma unroll
      for (int off = 1; off < 64; off <<= 1) m = fmaxf(m, __shfl_xor(m, off));
      if (lane == 0) wmax[w] = m;
      __syncthreads();
      m = fmaxf(fmaxf(wmax[0], wmax[1]), fmaxf(wmax[2], wmax[3]));
      float inv = 1.0f / m;
      #pragma unroll
      for (int rt = 0; rt < 2; ++rt)
        #pragma unroll
        for (int ct = 0; ct < 2; ++ct) acc[rt][ct] *= inv;
      logscale += logf(m);
    }

    int nxt = cur ^ 1;
    unsigned* L32 = (unsigned*)&L[nxt][0];
    #pragma unroll
    for (int rt = 0; rt < 2; ++rt)
      #pragma unroll
      for (int ct = 0; ct < 2; ++ct) {
        int row0 = wi * 32 + rt * 16 + lg * 4;   // 4-aligned
        int col = wj * 32 + ct * 16 + lr;
        int sidx = (col * 64 + row0) ^ ((col & 7) << 3);  // XOR hits bits>=3 only
        L32[(sidx >> 1) + 0] = cvtpk(acc[rt][ct][0], acc[rt][ct][1]);
        L32[(sidx >> 1) + 1] = cvtpk(acc[rt][ct][2], acc[rt][ct][3]);
      }
    __syncthreads();
    cur = nxt;
  }

  float* Mo = G2T + (((size_t)b * 32 + g) << 12);
  #pragma unroll
  for (int rt = 0; rt < 2; ++rt)
    #pragma unroll
    for (int ct = 0; ct < 2; ++ct)
      #pragma unroll
      for (int r = 0; r < 4; ++r) {
        int row = wi * 32 + rt * 16 + lg * 4 + r;
        int col = wj * 32 + ct * 16 + lr;
        Mo[row * 64 + col] = acc[rt][ct][r];
      }

  if (w == 0 && lane == 0) auxg[b * 32 + g] = logscale;
}

// ---------------- K6: final combine (32 group matrices per batch) -----------
__global__ __launch_bounds__(64) void mmm_combine_kernel(
    const float* __restrict__ pi_logits, const float* __restrict__ ehat,
    const float* __restrict__ cmax, const float* __restrict__ G2T,
    const float* __restrict__ auxg, float* __restrict__ out) {
  int b = blockIdx.x, lane = threadIdx.x;
  __shared__ __align__(16) float alds[64];

  float pv = pi_logits[lane];
  float mx = pv;
  #pragma unroll
  for (int off = 1; off < 64; off <<= 1) mx = fmaxf(mx, __shfl_xor(mx, off));
  float pe = expf(pv - mx);
  float ps = pe;
  #pragma unroll
  for (int off = 1; off < 64; off <<= 1) ps += __shfl_xor(ps, off);

  float a = (pe / ps) * ehat[(size_t)b * 4096 * 64 + lane];
  double logtot = (double)cmax[(size_t)b * 4096];
  alds[lane] = a;
  __builtin_amdgcn_wave_barrier();

  const float* Mb = G2T + (((size_t)b * 32) << 12) + lane * 64;
  f32x4 mc[16], mn[16];
  #pragma unroll
  for (int i = 0; i < 16; ++i) mc[i] = *(const f32x4*)&Mb[i * 4];

  for (int g = 0; g < 32; ++g) {
    if (g < 31) {
      const float* Mn = Mb + ((size_t)(g + 1) << 12);
      #pragma unroll
      for (int i = 0; i < 16; ++i) mn[i] = *(const f32x4*)&Mn[i * 4];
    }
    f32x4 a4 = {0.f, 0.f, 0.f, 0.f};
    #pragma unroll
    for (int i = 0; i < 16; ++i) {
      f32x4 av = *(const f32x4*)&alds[i * 4];
      a4 += mc[i] * av;
    }
    float acc = (a4[0] + a4[1]) + (a4[2] + a4[3]);
    float s = acc;
    #pragma unroll
    for (int off = 1; off < 64; off <<= 1) s += __shfl_xor(s, off);
    logtot += (double)(auxg[b * 32 + g] + logf(s));
    float an = acc / s;
    __builtin_amdgcn_wave_barrier();
    alds[lane] = an;
    __builtin_amdgcn_wave_barrier();
    #pragma unroll
    for (int i = 0; i < 16; ++i) mc[i] = mn[i];
  }
  if (lane == 0) out[b] = (float)logtot;
}

extern "C" void kernel_launch(void* const* d_in, const int* in_sizes, int n_in,
                              void* d_out, int out_size, void* d_ws, size_t ws_size,
                              hipStream_t stream) {
  const float* X      = (const float*)d_in[0];
  const float* pi_l   = (const float*)d_in[1];
  const float* tr_l   = (const float*)d_in[2];
  const float* wl     = (const float*)d_in[3];
  const float* means  = (const float*)d_in[4];
  const float* lvs    = (const float*)d_in[5];
  float* out = (float*)d_out;

  float* ws = (float*)d_ws;
  short* Gt      = (short*)ws;                 // 131072 shorts = 65536 f32
  float* const_c = ws + 65536;                 // 512
  short* WTbf    = (short*)(ws + 66048);       // 4096 shorts = 2048 f32
  float* cmaxp   = ws + 68608;                 // 32768
  float* ehat    = ws + 101376;                // 2097152
  short* XeP     = (short*)(ws + 2198528);     // 16.8 MB (8.4M shorts)
  short* NTb     = (short*)(ws + 2198528);     // aliases XeP; 256x8x4096 shorts
  float* aux     = ws + 6392832;               // 2048 (256 chunks x 8 b)
  float* G2T     = ws + 6396928;               // 1048576 (8 b x 32 g x 4096)
  float* auxg    = ws + 7445504;               // 256

  mmm_prep_fused<<<832, 256, 0, stream>>>(tr_l, means, lvs, wl, X,
                                          WTbf, Gt, const_c, XeP);
  mmm_emis_kernel<<<256, 512, 0, stream>>>(Gt, XeP, const_c, ehat, cmaxp);
  mmm_chunk_kernel<<<dim3(256, 8), 64, 0, stream>>>(WTbf, ehat, cmaxp, NTb, aux);
  mmm_merge_kernel<<<dim3(32, 8), 256, 0, stream>>>(NTb, aux, G2T, auxg);
  mmm_combine_kernel<<<8, 64, 0, stream>>>(pi_l, ehat, cmaxp, G2T, auxg, out);
}

// Round 11
// 101.815 us; speedup vs baseline: 1.2853x; 1.1169x over previous
//
#include <hip/hip_runtime.h>
#include <hip/hip_bf16.h>
#include <math.h>

#define LOG2PI_F 1.8378770664093453f

typedef __attribute__((ext_vector_type(8))) short bf16x8;
typedef __attribute__((ext_vector_type(4))) float f32x4;
typedef __attribute__((ext_vector_type(16))) float f32x16;

static __device__ inline short f2bf(float x) {
  __hip_bfloat16 h = __float2bfloat16(x);
  return *reinterpret_cast<short*>(&h);
}
// HW packed f32->bf16 (RNE). Session A/B (r1 vs r2) showed >= sw pack here.
static __device__ inline unsigned cvtpk(float lo, float hi) {
  unsigned r;
  asm("v_cvt_pk_bf16_f32 %0, %1, %2" : "=v"(r) : "v"(lo), "v"(hi));
  return r;
}
static __device__ inline f32x4 mfma16(bf16x8 a, bf16x8 b, f32x4 c) {
  return __builtin_amdgcn_mfma_f32_16x16x32_bf16(a, b, c, 0, 0, 0);
}
static __device__ inline f32x16 mfma32(bf16x8 a, bf16x8 b, f32x16 c) {
  return __builtin_amdgcn_mfma_f32_32x32x16_bf16(a, b, c, 0, 0, 0);
}

// ---------------- K012: fused prep (WTbf + Gt/const_c + XeP) ----------------
__global__ __launch_bounds__(256) void mmm_prep_fused(
    const float* __restrict__ tl, const float* __restrict__ means,
    const float* __restrict__ log_vars, const float* __restrict__ weight_logits,
    const float* __restrict__ X,
    short* __restrict__ WTbf, short* __restrict__ Gt,
    float* __restrict__ const_c, short* __restrict__ XeP) {
  __shared__ float red[4];
  int bid = blockIdx.x;
  int tid = threadIdx.x;

  if (bid < 64) {               // ---- K0 ----
    if (tid < 64) {
      int r = bid, lane = tid;
      float v = tl[r * 64 + lane];
      float mx = v;
      #pragma unroll
      for (int off = 1; off < 64; off <<= 1) mx = fmaxf(mx, __shfl_xor(mx, off));
      float e = expf(v - mx);
      float s = e;
      #pragma unroll
      for (int off = 1; off < 64; off <<= 1) s += __shfl_xor(s, off);
      WTbf[lane * 64 + r] = f2bf(e / s);
    }
    return;
  }

  if (bid < 320) {              // ---- K1 (2 sm per block) ----
    int h = tid >> 7, d = tid & 127;
    int sm = (bid - 64) * 2 + h;
    int s = sm >> 3, m = sm & 7;
    float lv = log_vars[sm * 128 + d];
    float iv = expf(-lv);
    float mu = means[sm * 128 + d];
    float miv = mu * iv;
    Gt[sm * 256 + d] = f2bf(miv);
    Gt[sm * 256 + 128 + d] = f2bf(-0.5f * iv);
    float v = mu * miv + lv;
    #pragma unroll
    for (int off = 1; off < 64; off <<= 1) v += __shfl_xor(v, off);
    if ((tid & 63) == 0) red[tid >> 6] = v;
    __syncthreads();
    if (d == 0) {
      float tot = red[2 * h] + red[2 * h + 1];
      float wl[8];
      float mx = -3.4e38f;
      #pragma unroll
      for (int j = 0; j < 8; ++j) { wl[j] = weight_logits[s * 8 + j]; mx = fmaxf(mx, wl[j]); }
      float sum = 0.f;
      #pragma unroll
      for (int j = 0; j < 8; ++j) sum += expf(wl[j] - mx);
      float lmw = wl[m] - mx - logf(sum);
      const_c[sm] = -0.5f * (tot + 128.0f * LOG2PI_F) + lmw;
    }
    return;
  }

  // ---- K2 ----
  int kbid = bid - 320;
  int q = kbid >> 7;
  int bt = ((kbid & 127) << 8) + tid;
  const float4* src = (const float4*)(X + (size_t)bt * 128 + q * 32);
  float xv[32];
  #pragma unroll
  for (int i = 0; i < 8; ++i) {
    float4 v = src[i];
    xv[4 * i] = v.x; xv[4 * i + 1] = v.y; xv[4 * i + 2] = v.z; xv[4 * i + 3] = v.w;
  }
  size_t base1 = ((size_t)q * 32768 + bt) * 32;
  size_t base2 = ((size_t)(q + 4) * 32768 + bt) * 32;
  int bx = bt & 3;
  #pragma unroll
  for (int g = 0; g < 4; ++g) {
    unsigned w1[4], w2[4];
    #pragma unroll
    for (int j = 0; j < 4; ++j) {
      float a = xv[g * 8 + 2 * j], c = xv[g * 8 + 2 * j + 1];
      w1[j] = cvtpk(a, c);
      w2[j] = cvtpk(a * a, c * c);
    }
    int gs = (g ^ bx) * 8;
    *(uint4*)&XeP[base1 + gs] = *(uint4*)w1;
    *(uint4*)&XeP[base2 + gs] = *(uint4*)w2;
  }
}

// ---------------- K34: FUSED emission GEMM + per-chunk scan ------------------
// r11: fuse emis+chunk. An emis block computes two 64-bt tiles = 2x4 chunks
// of 16 steps, and has exactly 8 waves -> phase 1 writes e=exp(lse-colmax)
// into LDS (elds[2][64 t][64 s]) instead of global ehat; phase 2 runs one
// 16-step chunk per wave reading e straight from LDS. Kills one launch gap
// + 17 MB ehat/cmax round-trip + chunk's e-staging. Only the t=0 emission
// column + t=0 colmax still go to global (ehat0[8][64], cmax0[8]) for K6.
// NOTE: NTb must NOT alias XeP here (other blocks still read XeP while we
// write NTb) — un-aliased in the workspace layout.
__global__ __launch_bounds__(512) void mmm_emischunk_kernel(
    const short* __restrict__ Gt, const short* __restrict__ XeP,
    const float* __restrict__ const_c, const short* __restrict__ WTbf,
    short* __restrict__ NTb, float* __restrict__ aux,
    float* __restrict__ ehat0, float* __restrict__ cmax0) {
  __shared__ __align__(16) short Bt[16384];      // 32 KB
  __shared__ __align__(16) float ccs[512];
  __shared__ float wavemax[8][64];
  __shared__ float colmax2[2][64];
  __shared__ __align__(16) float elds[2][4096];  // 2 tiles x 64 t x 64 s = 32 KB
  int tid = threadIdx.x;
  int w = tid >> 6, lane = tid & 63, lr = lane & 15, lg = lane >> 4;
  int T0 = (blockIdx.x & 63) * 64;               // same for both tiles

  ccs[tid] = const_c[tid];

  bf16x8 gf[4][8];
  #pragma unroll
  for (int rt = 0; rt < 4; ++rt) {
    int row = w * 64 + rt * 16 + lr;
    #pragma unroll
    for (int kc = 0; kc < 8; ++kc)
      gf[rt][kc] = *(const bf16x8*)&Gt[row * 256 + kc * 32 + lg * 8];
  }

  uint4 sreg[4];
  {
    size_t bt0 = (size_t)blockIdx.x * 64;
    #pragma unroll
    for (int r = 0; r < 4; ++r) {
      int ofs = r * 8192 + tid * 16;
      int kb2 = ofs >> 12, rem = ofs & 4095;
      sreg[r] = *(const uint4*)((const char*)XeP + ((size_t)kb2 * 32768 + bt0) * 64 + rem);
    }
  }

  // -------- phase 1: emission for both tiles, e into LDS --------
  for (int it = 0; it < 2; ++it) {
    int bcur = (blockIdx.x + it * 256) >> 6;     // batch of this tile
    __syncthreads();
    #pragma unroll
    for (int r = 0; r < 4; ++r)
      *(uint4*)((char*)Bt + r * 8192 + tid * 16) = sreg[r];
    __syncthreads();
    if (it == 0) {
      size_t bt0n = ((size_t)blockIdx.x + 256) * 64;
      #pragma unroll
      for (int r = 0; r < 4; ++r) {
        int ofs = r * 8192 + tid * 16;
        int kb2 = ofs >> 12, rem = ofs & 4095;
        sreg[r] = *(const uint4*)((const char*)XeP + ((size_t)kb2 * 32768 + bt0n) * 64 + rem);
      }
    }

    f32x4 acc[4][4];
    #pragma unroll
    for (int rt = 0; rt < 4; ++rt)
      #pragma unroll
      for (int ct = 0; ct < 4; ++ct)
        acc[rt][ct] = (f32x4){0.f, 0.f, 0.f, 0.f};

    #pragma unroll
    for (int kc = 0; kc < 8; ++kc) {
      bf16x8 bfr[4];
      #pragma unroll
      for (int ct = 0; ct < 4; ++ct) {
        int btL = ct * 16 + lr;
        bfr[ct] = *(const bf16x8*)&Bt[kc * 2048 + btL * 32 + ((lg ^ (btL & 3)) * 8)];
      }
      #pragma unroll
      for (int rt = 0; rt < 4; ++rt)
        #pragma unroll
        for (int ct = 0; ct < 4; ++ct)
          acc[rt][ct] = mfma16(gf[rt][kc], bfr[ct], acc[rt][ct]);
    }

    float lse[4][4];
    #pragma unroll
    for (int rt = 0; rt < 4; ++rt) {
      f32x4 cc = *(f32x4*)&ccs[w * 64 + rt * 16 + lg * 4];
      #pragma unroll
      for (int ct = 0; ct < 4; ++ct) {
        f32x4 v = acc[rt][ct] + cc;
        float mx = fmaxf(fmaxf(v[0], v[1]), fmaxf(v[2], v[3]));
        mx = fmaxf(mx, __shfl_xor(mx, 16));
        float sum = expf(v[0] - mx) + expf(v[1] - mx) + expf(v[2] - mx) + expf(v[3] - mx);
        sum += __shfl_xor(sum, 16);
        lse[rt][ct] = mx + logf(sum);
      }
    }
    #pragma unroll
    for (int ct = 0; ct < 4; ++ct) {
      float cm = fmaxf(fmaxf(lse[0][ct], lse[1][ct]), fmaxf(lse[2][ct], lse[3][ct]));
      cm = fmaxf(cm, __shfl_xor(cm, 32));
      if (lg == 0) wavemax[w][ct * 16 + lr] = cm;
    }
    __syncthreads();
    if (w == 0) {
      float cm = wavemax[0][lane];
      #pragma unroll
      for (int ww = 1; ww < 8; ++ww) cm = fmaxf(cm, wavemax[ww][lane]);
      colmax2[it][lane] = cm;
      if (lane == 0 && T0 == 0) cmax0[bcur] = cm;   // lane 0 holds t_local=0 col
    }
    __syncthreads();
    #pragma unroll
    for (int ct = 0; ct < 4; ++ct) {
      float cm = colmax2[it][ct * 16 + lr];
      #pragma unroll
      for (int rt = 0; rt < 4; ++rt) {
        float v = expf(lse[rt][ct] - cm);
        if (!(lg & 1)) {
          int s = w * 8 + rt * 2 + (lg >> 1);
          elds[it][(ct * 16 + lr) * 64 + s] = v;
          if (T0 == 0 && ct == 0 && lr == 0) ehat0[bcur * 64 + s] = v;
        }
      }
    }
  }
  __syncthreads();  // elds + colmax2 complete

  // -------- phase 2: per-wave 16-step chunk scan (e from LDS) --------
  int tl = w >> 2, q = w & 3;
  int bS = (blockIdx.x + tl * 256) >> 6;
  int c = (T0 >> 4) + q;                 // chunk index within batch
  int t0l, nsteps;
  if (c == 0) { t0l = 1; nsteps = 15; } else { t0l = q * 16; nsteps = 16; }
  int l31 = lane & 31, hi = lane >> 5;
  const float* etile = &elds[tl][0];

  // A = W^T: af[wi][kb], row = wi*32+l31, k = kb*16 + hi*8 + j
  bf16x8 af[2][4];
  #pragma unroll
  for (int wi = 0; wi < 2; ++wi)
    #pragma unroll
    for (int kb = 0; kb < 4; ++kb)
      af[wi][kb] = *(const bf16x8*)&WTbf[(wi * 32 + l31) * 64 + kb * 16 + hi * 8];

  // packed state: P[s][cm][q][p] = bf16 rows {32cm+8q+4hi+2p, +1} at col s*32+l31
  unsigned P[2][2][4][2];
  #pragma unroll
  for (int s = 0; s < 2; ++s) {
    int col = s * 32 + l31;
    #pragma unroll
    for (int cm = 0; cm < 2; ++cm)
      #pragma unroll
      for (int qq = 0; qq < 4; ++qq)
        #pragma unroll
        for (int p = 0; p < 2; ++p) {
          int row = 32 * cm + 8 * qq + 4 * hi + 2 * p;
          unsigned lo = (row == col) ? 0x3F80u : 0u;       // bf16(1.0)
          unsigned h16 = (row + 1 == col) ? 0x3F80u : 0u;
          P[s][cm][qq][p] = lo | (h16 << 16);
        }
  }

  float logscale = 0.f;
  f32x4 ecur[2][4], enxt[2][4];
  #pragma unroll
  for (int cm = 0; cm < 2; ++cm)
    #pragma unroll
    for (int qq = 0; qq < 4; ++qq)
      ecur[cm][qq] = *(const f32x4*)&etile[t0l * 64 + cm * 32 + qq * 8 + hi * 4];

  for (int i = 0; i < nsteps; ++i) {
    if (i + 1 < nsteps) {  // prefetch next step's e from LDS
      #pragma unroll
      for (int cm = 0; cm < 2; ++cm)
        #pragma unroll
        for (int qq = 0; qq < 4; ++qq)
          enxt[cm][qq] = *(const f32x4*)&etile[(t0l + i + 1) * 64 + cm * 32 + qq * 8 + hi * 4];
    }

    __builtin_amdgcn_s_setprio(1);
    #pragma unroll
    for (int s = 0; s < 2; ++s) {
      // B[kb]: k = kb*16 + 8*hi + j; one permlane32_swap per (quad-pair, p)
      bf16x8 B[4];
      #pragma unroll
      for (int kb = 0; kb < 4; ++kb) {
        int cm = kb >> 1, kbl = kb & 1;
        int4 wrd;
        #pragma unroll
        for (int p = 0; p < 2; ++p) {
          unsigned avv = P[s][cm][2 * kbl + 1][p];
          unsigned bvv = P[s][cm][2 * kbl][p];
          asm("v_permlane32_swap_b32 %0, %1" : "+v"(avv), "+v"(bvv));
          if (p == 0) { wrd.x = (int)bvv; wrd.z = (int)avv; }
          else        { wrd.y = (int)bvv; wrd.w = (int)avv; }
        }
        B[kb] = *(bf16x8*)&wrd;
      }

      f32x16 d0, d1;
      #pragma unroll
      for (int r = 0; r < 16; ++r) { d0[r] = 0.f; d1[r] = 0.f; }
      #pragma unroll
      for (int kb = 0; kb < 4; ++kb) {
        d0 = mfma32(af[0][kb], B[kb], d0);
        d1 = mfma32(af[1][kb], B[kb], d1);
      }

      // P = pack(d * e): reg 4q+s_ -> row 32cm+8q+4hi+s_
      #pragma unroll
      for (int qq = 0; qq < 4; ++qq)
        #pragma unroll
        for (int p = 0; p < 2; ++p) {
          P[s][0][qq][p] = cvtpk(d0[4 * qq + 2 * p] * ecur[0][qq][2 * p],
                                 d0[4 * qq + 2 * p + 1] * ecur[0][qq][2 * p + 1]);
          P[s][1][qq][p] = cvtpk(d1[4 * qq + 2 * p] * ecur[1][qq][2 * p],
                                 d1[4 * qq + 2 * p + 1] * ecur[1][qq][2 * p + 1]);
        }
    }
    __builtin_amdgcn_s_setprio(0);

    if ((i & 7) == 7) {  // rescale (i=7 and i=15; final one normalizes NTb)
      float m = 0.f;
      #pragma unroll
      for (int s = 0; s < 2; ++s)
        #pragma unroll
        for (int cm = 0; cm < 2; ++cm)
          #pragma unroll
          for (int qq = 0; qq < 4; ++qq)
            #pragma unroll
            for (int p = 0; p < 2; ++p) {
              unsigned u = P[s][cm][qq][p];
              m = fmaxf(m, __uint_as_float(u << 16));
              m = fmaxf(m, __uint_as_float(u & 0xffff0000u));
            }
      #pragma unroll
      for (int off = 1; off < 64; off <<= 1) m = fmaxf(m, __shfl_xor(m, off));
      float inv = 1.0f / m;
      #pragma unroll
      for (int s = 0; s < 2; ++s)
        #pragma unroll
        for (int cm = 0; cm < 2; ++cm)
          #pragma unroll
          for (int qq = 0; qq < 4; ++qq)
            #pragma unroll
            for (int p = 0; p < 2; ++p) {
              unsigned u = P[s][cm][qq][p];
              P[s][cm][qq][p] = cvtpk(__uint_as_float(u << 16) * inv,
                                      __uint_as_float(u & 0xffff0000u) * inv);
            }
      logscale += logf(m);
    }

    #pragma unroll
    for (int cm = 0; cm < 2; ++cm)
      #pragma unroll
      for (int qq = 0; qq < 4; ++qq) ecur[cm][qq] = enxt[cm][qq];
  }

  // store N_c bf16 row-major [row][col]
  unsigned short* No = (unsigned short*)(NTb + (((size_t)bS * 256 + c) << 12));
  #pragma unroll
  for (int s = 0; s < 2; ++s)
    #pragma unroll
    for (int cm = 0; cm < 2; ++cm)
      #pragma unroll
      for (int qq = 0; qq < 4; ++qq)
        #pragma unroll
        for (int p = 0; p < 2; ++p) {
          int row = 32 * cm + 8 * qq + 4 * hi + 2 * p;
          int col = s * 32 + l31;
          unsigned u = P[s][cm][qq][p];
          No[row * 64 + col] = (unsigned short)(u & 0xffffu);
          No[(row + 1) * 64 + col] = (unsigned short)(u >> 16);
        }

  // aux[b][chunk] = sum of colmax over chunk's t-range + chunk logscale
  float cs = (lane < nsteps) ? colmax2[tl][t0l + lane] : 0.f;
  #pragma unroll
  for (int off = 1; off < 64; off <<= 1) cs += __shfl_xor(cs, off);
  if (lane == 0) aux[(size_t)bS * 256 + c] = cs + logscale;
}

// ---------------- K5: merge 8 chunks -> group matrix (32 groups/batch) ------
__global__ __launch_bounds__(256) void mmm_merge_kernel(
    const short* __restrict__ NTb, const float* __restrict__ aux,
    float* __restrict__ G2T, float* __restrict__ auxg) {
  int g = blockIdx.x, b = blockIdx.y;
  int tid = threadIdx.x;
  int w = tid >> 6, lane = tid & 63;
  int wi = w >> 1, wj = w & 1;
  int lr = lane & 15, lg = lane >> 4;

  __shared__ __align__(16) short L[2][4096];
  __shared__ float wmax[4];

  for (int idx = tid; idx < 4096; idx += 256) {
    int j = idx >> 6, k = idx & 63;
    L[0][idx ^ ((j & 7) << 3)] = (j == k) ? (short)0x3F80 : (short)0;
  }
  __syncthreads();

  int cbase = b * 256 + g * 8;

  float logscale = 0.f;
  int cur = 0;
  f32x4 acc[2][2];

  bf16x8 apre[2][2];
  {
    const short* Mc = NTb + ((size_t)cbase << 12);
    #pragma unroll
    for (int rt = 0; rt < 2; ++rt)
      #pragma unroll
      for (int kc = 0; kc < 2; ++kc)
        apre[rt][kc] = *(const bf16x8*)&Mc[(wi * 32 + rt * 16 + lr) * 64 + kc * 32 + lg * 8];
  }

  for (int cc = 0; cc < 8; ++cc) {
    bf16x8 acur[2][2];
    #pragma unroll
    for (int rt = 0; rt < 2; ++rt)
      #pragma unroll
      for (int kc = 0; kc < 2; ++kc) acur[rt][kc] = apre[rt][kc];
    if (cc < 7) {
      const short* Mc = NTb + ((size_t)(cbase + cc + 1) << 12);
      #pragma unroll
      for (int rt = 0; rt < 2; ++rt)
        #pragma unroll
        for (int kc = 0; kc < 2; ++kc)
          apre[rt][kc] = *(const bf16x8*)&Mc[(wi * 32 + rt * 16 + lr) * 64 + kc * 32 + lg * 8];
    }

    logscale += aux[cbase + cc];

    bf16x8 bfr[2][2];
    #pragma unroll
    for (int ct = 0; ct < 2; ++ct) {
      int j = wj * 32 + ct * 16 + lr;
      int sw = (j & 7) << 3;
      #pragma unroll
      for (int kc = 0; kc < 2; ++kc)
        bfr[ct][kc] = *(const bf16x8*)&L[cur][(j * 64 + kc * 32 + lg * 8) ^ sw];
    }

    #pragma unroll
    for (int rt = 0; rt < 2; ++rt)
      #pragma unroll
      for (int ct = 0; ct < 2; ++ct) {
        f32x4 c = {0.f, 0.f, 0.f, 0.f};
        c = mfma16(acur[rt][0], bfr[ct][0], c);
        c = mfma16(acur[rt][1], bfr[ct][1], c);
        acc[rt][ct] = c;
      }

    if ((cc & 3) == 3) {  // rescale every 4th product (cc=3,7)
      float m = 0.f;
      #pragma unroll
      for (int rt = 0; rt < 2; ++rt)
        #pragma unroll
        for (int ct = 0; ct < 2; ++ct)
          #pragma unroll
          for (int r = 0; r < 4; ++r) m = fmaxf(m, acc[rt][ct][r]);
      #pragma unroll
      for (int off = 1; off < 64; off <<= 1) m = fmaxf(m, __shfl_xor(m, off));
      if (lane == 0) wmax[w] = m;
      __syncthreads();
      m = fmaxf(fmaxf(wmax[0], wmax[1]), fmaxf(wmax[2], wmax[3]));
      float inv = 1.0f / m;
      #pragma unroll
      for (int rt = 0; rt < 2; ++rt)
        #pragma unroll
        for (int ct = 0; ct < 2; ++ct) acc[rt][ct] *= inv;
      logscale += logf(m);
    }

    int nxt = cur ^ 1;
    unsigned* L32 = (unsigned*)&L[nxt][0];
    #pragma unroll
    for (int rt = 0; rt < 2; ++rt)
      #pragma unroll
      for (int ct = 0; ct < 2; ++ct) {
        int row0 = wi * 32 + rt * 16 + lg * 4;   // 4-aligned
        int col = wj * 32 + ct * 16 + lr;
        int sidx = (col * 64 + row0) ^ ((col & 7) << 3);  // XOR hits bits>=3 only
        L32[(sidx >> 1) + 0] = cvtpk(acc[rt][ct][0], acc[rt][ct][1]);
        L32[(sidx >> 1) + 1] = cvtpk(acc[rt][ct][2], acc[rt][ct][3]);
      }
    __syncthreads();
    cur = nxt;
  }

  float* Mo = G2T + (((size_t)b * 32 + g) << 12);
  #pragma unroll
  for (int rt = 0; rt < 2; ++rt)
    #pragma unroll
    for (int ct = 0; ct < 2; ++ct)
      #pragma unroll
      for (int r = 0; r < 4; ++r) {
        int row = wi * 32 + rt * 16 + lg * 4 + r;
        int col = wj * 32 + ct * 16 + lr;
        Mo[row * 64 + col] = acc[rt][ct][r];
      }

  if (w == 0 && lane == 0) auxg[b * 32 + g] = logscale;
}

// ---------------- K6: final combine (32 group matrices per batch) -----------
__global__ __launch_bounds__(64) void mmm_combine_kernel(
    const float* __restrict__ pi_logits, const float* __restrict__ ehat0,
    const float* __restrict__ cmax0, const float* __restrict__ G2T,
    const float* __restrict__ auxg, float* __restrict__ out) {
  int b = blockIdx.x, lane = threadIdx.x;
  __shared__ __align__(16) float alds[64];

  float pv = pi_logits[lane];
  float mx = pv;
  #pragma unroll
  for (int off = 1; off < 64; off <<= 1) mx = fmaxf(mx, __shfl_xor(mx, off));
  float pe = expf(pv - mx);
  float ps = pe;
  #pragma unroll
  for (int off = 1; off < 64; off <<= 1) ps += __shfl_xor(ps, off);

  float a = (pe / ps) * ehat0[b * 64 + lane];
  double logtot = (double)cmax0[b];
  alds[lane] = a;
  __builtin_amdgcn_wave_barrier();

  const float* Mb = G2T + (((size_t)b * 32) << 12) + lane * 64;
  f32x4 mc[16], mn[16];
  #pragma unroll
  for (int i = 0; i < 16; ++i) mc[i] = *(const f32x4*)&Mb[i * 4];

  for (int g = 0; g < 32; ++g) {
    if (g < 31) {
      const float* Mn = Mb + ((size_t)(g + 1) << 12);
      #pragma unroll
      for (int i = 0; i < 16; ++i) mn[i] = *(const f32x4*)&Mn[i * 4];
    }
    f32x4 a4 = {0.f, 0.f, 0.f, 0.f};
    #pragma unroll
    for (int i = 0; i < 16; ++i) {
      f32x4 av = *(const f32x4*)&alds[i * 4];
      a4 += mc[i] * av;
    }
    float acc = (a4[0] + a4[1]) + (a4[2] + a4[3]);
    float s = acc;
    #pragma unroll
    for (int off = 1; off < 64; off <<= 1) s += __shfl_xor(s, off);
    logtot += (double)(auxg[b * 32 + g] + logf(s));
    float an = acc / s;
    __builtin_amdgcn_wave_barrier();
    alds[lane] = an;
    __builtin_amdgcn_wave_barrier();
    #pragma unroll
    for (int i = 0; i < 16; ++i) mc[i] = mn[i];
  }
  if (lane == 0) out[b] = (float)logtot;
}

extern "C" void kernel_launch(void* const* d_in, const int* in_sizes, int n_in,
                              void* d_out, int out_size, void* d_ws, size_t ws_size,
                              hipStream_t stream) {
  const float* X      = (const float*)d_in[0];
  const float* pi_l   = (const float*)d_in[1];
  const float* tr_l   = (const float*)d_in[2];
  const float* wl     = (const float*)d_in[3];
  const float* means  = (const float*)d_in[4];
  const float* lvs    = (const float*)d_in[5];
  float* out = (float*)d_out;

  float* ws = (float*)d_ws;
  short* Gt      = (short*)ws;                 // 131072 shorts = 65536 f32
  float* const_c = ws + 65536;                 // 512
  short* WTbf    = (short*)(ws + 66048);       // 4096 shorts = 2048 f32
  float* ehat0   = ws + 68096;                 // 512 (8 b x 64 states, t=0)
  float* cmax0   = ws + 68608;                 // 8 (t=0 colmax per b)
  short* XeP     = (short*)(ws + 2198528);     // 16.8 MB -> ends 6392832
  short* NTb     = (short*)(ws + 6392832);     // 16.8 MB (NOT aliasing XeP!)
  float* aux     = ws + 10587136;              // 2048 (256 chunks x 8 b)
  float* G2T     = ws + 10591232;              // 1048576 (8 b x 32 g x 4096)
  float* auxg    = ws + 11639808;              // 256

  mmm_prep_fused<<<832, 256, 0, stream>>>(tr_l, means, lvs, wl, X,
                                          WTbf, Gt, const_c, XeP);
  mmm_emischunk_kernel<<<256, 512, 0, stream>>>(Gt, XeP, const_c, WTbf,
                                                NTb, aux, ehat0, cmax0);
  mmm_merge_kernel<<<dim3(32, 8), 256, 0, stream>>>(NTb, aux, G2T, auxg);
  mmm_combine_kernel<<<8, 64, 0, stream>>>(pi_l, ehat0, cmax0, G2T, auxg, out);
}

// Round 12
// 100.387 us; speedup vs baseline: 1.3036x; 1.0142x over previous
//
#include <hip/hip_runtime.h>
#include <hip/hip_bf16.h>
#include <math.h>

#define LOG2PI_F 1.8378770664093453f
#define EPAD 68   // elds row stride in floats: 68*4=272B keeps 16B alignment;
                  // bank advance 4/row -> 2-way aliasing (free, m136) vs the
                  // 16-way conflict of stride 64 (2.49M conflict cycles, r11)

typedef __attribute__((ext_vector_type(8))) short bf16x8;
typedef __attribute__((ext_vector_type(4))) float f32x4;
typedef __attribute__((ext_vector_type(16))) float f32x16;

static __device__ inline short f2bf(float x) {
  __hip_bfloat16 h = __float2bfloat16(x);
  return *reinterpret_cast<short*>(&h);
}
// HW packed f32->bf16 (RNE). Session A/B (r1 vs r2) showed >= sw pack here.
static __device__ inline unsigned cvtpk(float lo, float hi) {
  unsigned r;
  asm("v_cvt_pk_bf16_f32 %0, %1, %2" : "=v"(r) : "v"(lo), "v"(hi));
  return r;
}
static __device__ inline f32x4 mfma16(bf16x8 a, bf16x8 b, f32x4 c) {
  return __builtin_amdgcn_mfma_f32_16x16x32_bf16(a, b, c, 0, 0, 0);
}
static __device__ inline f32x16 mfma32(bf16x8 a, bf16x8 b, f32x16 c) {
  return __builtin_amdgcn_mfma_f32_32x32x16_bf16(a, b, c, 0, 0, 0);
}

// ---------------- K012: fused prep (WTbf + Gt/const_c + XeP) ----------------
__global__ __launch_bounds__(256) void mmm_prep_fused(
    const float* __restrict__ tl, const float* __restrict__ means,
    const float* __restrict__ log_vars, const float* __restrict__ weight_logits,
    const float* __restrict__ X,
    short* __restrict__ WTbf, short* __restrict__ Gt,
    float* __restrict__ const_c, short* __restrict__ XeP) {
  __shared__ float red[4];
  int bid = blockIdx.x;
  int tid = threadIdx.x;

  if (bid < 64) {               // ---- K0 ----
    if (tid < 64) {
      int r = bid, lane = tid;
      float v = tl[r * 64 + lane];
      float mx = v;
      #pragma unroll
      for (int off = 1; off < 64; off <<= 1) mx = fmaxf(mx, __shfl_xor(mx, off));
      float e = expf(v - mx);
      float s = e;
      #pragma unroll
      for (int off = 1; off < 64; off <<= 1) s += __shfl_xor(s, off);
      WTbf[lane * 64 + r] = f2bf(e / s);
    }
    return;
  }

  if (bid < 320) {              // ---- K1 (2 sm per block) ----
    int h = tid >> 7, d = tid & 127;
    int sm = (bid - 64) * 2 + h;
    int s = sm >> 3, m = sm & 7;
    float lv = log_vars[sm * 128 + d];
    float iv = expf(-lv);
    float mu = means[sm * 128 + d];
    float miv = mu * iv;
    Gt[sm * 256 + d] = f2bf(miv);
    Gt[sm * 256 + 128 + d] = f2bf(-0.5f * iv);
    float v = mu * miv + lv;
    #pragma unroll
    for (int off = 1; off < 64; off <<= 1) v += __shfl_xor(v, off);
    if ((tid & 63) == 0) red[tid >> 6] = v;
    __syncthreads();
    if (d == 0) {
      float tot = red[2 * h] + red[2 * h + 1];
      float wl[8];
      float mx = -3.4e38f;
      #pragma unroll
      for (int j = 0; j < 8; ++j) { wl[j] = weight_logits[s * 8 + j]; mx = fmaxf(mx, wl[j]); }
      float sum = 0.f;
      #pragma unroll
      for (int j = 0; j < 8; ++j) sum += expf(wl[j] - mx);
      float lmw = wl[m] - mx - logf(sum);
      const_c[sm] = -0.5f * (tot + 128.0f * LOG2PI_F) + lmw;
    }
    return;
  }

  // ---- K2 ----
  int kbid = bid - 320;
  int q = kbid >> 7;
  int bt = ((kbid & 127) << 8) + tid;
  const float4* src = (const float4*)(X + (size_t)bt * 128 + q * 32);
  float xv[32];
  #pragma unroll
  for (int i = 0; i < 8; ++i) {
    float4 v = src[i];
    xv[4 * i] = v.x; xv[4 * i + 1] = v.y; xv[4 * i + 2] = v.z; xv[4 * i + 3] = v.w;
  }
  size_t base1 = ((size_t)q * 32768 + bt) * 32;
  size_t base2 = ((size_t)(q + 4) * 32768 + bt) * 32;
  int bx = bt & 3;
  #pragma unroll
  for (int g = 0; g < 4; ++g) {
    unsigned w1[4], w2[4];
    #pragma unroll
    for (int j = 0; j < 4; ++j) {
      float a = xv[g * 8 + 2 * j], c = xv[g * 8 + 2 * j + 1];
      w1[j] = cvtpk(a, c);
      w2[j] = cvtpk(a * a, c * c);
    }
    int gs = (g ^ bx) * 8;
    *(uint4*)&XeP[base1 + gs] = *(uint4*)w1;
    *(uint4*)&XeP[base2 + gs] = *(uint4*)w2;
  }
}

// ---------------- K34: FUSED emission GEMM + per-chunk scan ------------------
// r12: pad elds rows to EPAD=68 floats. r11's stride-64 layout put all 16
// scatter-write lanes on one bank (SQ_LDS_BANK_CONFLICT=2.49M); stride 68
// spreads rows across 8 banks (2-way aliasing = free). Rows stay 16B-aligned
// so phase-2 f32x4 broadcast reads are unchanged. LDS 70144->72192, still
// 2 blocks/CU.
__global__ __launch_bounds__(512) void mmm_emischunk_kernel(
    const short* __restrict__ Gt, const short* __restrict__ XeP,
    const float* __restrict__ const_c, const short* __restrict__ WTbf,
    short* __restrict__ NTb, float* __restrict__ aux,
    float* __restrict__ ehat0, float* __restrict__ cmax0) {
  __shared__ __align__(16) short Bt[16384];      // 32 KB
  __shared__ __align__(16) float ccs[512];
  __shared__ float wavemax[8][64];
  __shared__ float colmax2[2][64];
  __shared__ __align__(16) float elds[2][64 * EPAD];  // 2 x 64 t x EPAD
  int tid = threadIdx.x;
  int w = tid >> 6, lane = tid & 63, lr = lane & 15, lg = lane >> 4;
  int T0 = (blockIdx.x & 63) * 64;               // same for both tiles

  ccs[tid] = const_c[tid];

  bf16x8 gf[4][8];
  #pragma unroll
  for (int rt = 0; rt < 4; ++rt) {
    int row = w * 64 + rt * 16 + lr;
    #pragma unroll
    for (int kc = 0; kc < 8; ++kc)
      gf[rt][kc] = *(const bf16x8*)&Gt[row * 256 + kc * 32 + lg * 8];
  }

  uint4 sreg[4];
  {
    size_t bt0 = (size_t)blockIdx.x * 64;
    #pragma unroll
    for (int r = 0; r < 4; ++r) {
      int ofs = r * 8192 + tid * 16;
      int kb2 = ofs >> 12, rem = ofs & 4095;
      sreg[r] = *(const uint4*)((const char*)XeP + ((size_t)kb2 * 32768 + bt0) * 64 + rem);
    }
  }

  // -------- phase 1: emission for both tiles, e into LDS --------
  for (int it = 0; it < 2; ++it) {
    int bcur = (blockIdx.x + it * 256) >> 6;     // batch of this tile
    __syncthreads();
    #pragma unroll
    for (int r = 0; r < 4; ++r)
      *(uint4*)((char*)Bt + r * 8192 + tid * 16) = sreg[r];
    __syncthreads();
    if (it == 0) {
      size_t bt0n = ((size_t)blockIdx.x + 256) * 64;
      #pragma unroll
      for (int r = 0; r < 4; ++r) {
        int ofs = r * 8192 + tid * 16;
        int kb2 = ofs >> 12, rem = ofs & 4095;
        sreg[r] = *(const uint4*)((const char*)XeP + ((size_t)kb2 * 32768 + bt0n) * 64 + rem);
      }
    }

    f32x4 acc[4][4];
    #pragma unroll
    for (int rt = 0; rt < 4; ++rt)
      #pragma unroll
      for (int ct = 0; ct < 4; ++ct)
        acc[rt][ct] = (f32x4){0.f, 0.f, 0.f, 0.f};

    #pragma unroll
    for (int kc = 0; kc < 8; ++kc) {
      bf16x8 bfr[4];
      #pragma unroll
      for (int ct = 0; ct < 4; ++ct) {
        int btL = ct * 16 + lr;
        bfr[ct] = *(const bf16x8*)&Bt[kc * 2048 + btL * 32 + ((lg ^ (btL & 3)) * 8)];
      }
      #pragma unroll
      for (int rt = 0; rt < 4; ++rt)
        #pragma unroll
        for (int ct = 0; ct < 4; ++ct)
          acc[rt][ct] = mfma16(gf[rt][kc], bfr[ct], acc[rt][ct]);
    }

    float lse[4][4];
    #pragma unroll
    for (int rt = 0; rt < 4; ++rt) {
      f32x4 cc = *(f32x4*)&ccs[w * 64 + rt * 16 + lg * 4];
      #pragma unroll
      for (int ct = 0; ct < 4; ++ct) {
        f32x4 v = acc[rt][ct] + cc;
        float mx = fmaxf(fmaxf(v[0], v[1]), fmaxf(v[2], v[3]));
        mx = fmaxf(mx, __shfl_xor(mx, 16));
        float sum = expf(v[0] - mx) + expf(v[1] - mx) + expf(v[2] - mx) + expf(v[3] - mx);
        sum += __shfl_xor(sum, 16);
        lse[rt][ct] = mx + logf(sum);
      }
    }
    #pragma unroll
    for (int ct = 0; ct < 4; ++ct) {
      float cm = fmaxf(fmaxf(lse[0][ct], lse[1][ct]), fmaxf(lse[2][ct], lse[3][ct]));
      cm = fmaxf(cm, __shfl_xor(cm, 32));
      if (lg == 0) wavemax[w][ct * 16 + lr] = cm;
    }
    __syncthreads();
    if (w == 0) {
      float cm = wavemax[0][lane];
      #pragma unroll
      for (int ww = 1; ww < 8; ++ww) cm = fmaxf(cm, wavemax[ww][lane]);
      colmax2[it][lane] = cm;
      if (lane == 0 && T0 == 0) cmax0[bcur] = cm;   // lane 0 holds t_local=0 col
    }
    __syncthreads();
    #pragma unroll
    for (int ct = 0; ct < 4; ++ct) {
      float cm = colmax2[it][ct * 16 + lr];
      #pragma unroll
      for (int rt = 0; rt < 4; ++rt) {
        float v = expf(lse[rt][ct] - cm);
        if (!(lg & 1)) {
          int s = w * 8 + rt * 2 + (lg >> 1);
          elds[it][(ct * 16 + lr) * EPAD + s] = v;
          if (T0 == 0 && ct == 0 && lr == 0) ehat0[bcur * 64 + s] = v;
        }
      }
    }
  }
  __syncthreads();  // elds + colmax2 complete

  // -------- phase 2: per-wave 16-step chunk scan (e from LDS) --------
  int tl = w >> 2, q = w & 3;
  int bS = (blockIdx.x + tl * 256) >> 6;
  int c = (T0 >> 4) + q;                 // chunk index within batch
  int t0l, nsteps;
  if (c == 0) { t0l = 1; nsteps = 15; } else { t0l = q * 16; nsteps = 16; }
  int l31 = lane & 31, hi = lane >> 5;
  const float* etile = &elds[tl][0];

  // A = W^T: af[wi][kb], row = wi*32+l31, k = kb*16 + hi*8 + j
  bf16x8 af[2][4];
  #pragma unroll
  for (int wi = 0; wi < 2; ++wi)
    #pragma unroll
    for (int kb = 0; kb < 4; ++kb)
      af[wi][kb] = *(const bf16x8*)&WTbf[(wi * 32 + l31) * 64 + kb * 16 + hi * 8];

  // packed state: P[s][cm][q][p] = bf16 rows {32cm+8q+4hi+2p, +1} at col s*32+l31
  unsigned P[2][2][4][2];
  #pragma unroll
  for (int s = 0; s < 2; ++s) {
    int col = s * 32 + l31;
    #pragma unroll
    for (int cm = 0; cm < 2; ++cm)
      #pragma unroll
      for (int qq = 0; qq < 4; ++qq)
        #pragma unroll
        for (int p = 0; p < 2; ++p) {
          int row = 32 * cm + 8 * qq + 4 * hi + 2 * p;
          unsigned lo = (row == col) ? 0x3F80u : 0u;       // bf16(1.0)
          unsigned h16 = (row + 1 == col) ? 0x3F80u : 0u;
          P[s][cm][qq][p] = lo | (h16 << 16);
        }
  }

  float logscale = 0.f;
  f32x4 ecur[2][4], enxt[2][4];
  #pragma unroll
  for (int cm = 0; cm < 2; ++cm)
    #pragma unroll
    for (int qq = 0; qq < 4; ++qq)
      ecur[cm][qq] = *(const f32x4*)&etile[t0l * EPAD + cm * 32 + qq * 8 + hi * 4];

  for (int i = 0; i < nsteps; ++i) {
    if (i + 1 < nsteps) {  // prefetch next step's e from LDS
      #pragma unroll
      for (int cm = 0; cm < 2; ++cm)
        #pragma unroll
        for (int qq = 0; qq < 4; ++qq)
          enxt[cm][qq] = *(const f32x4*)&etile[(t0l + i + 1) * EPAD + cm * 32 + qq * 8 + hi * 4];
    }

    __builtin_amdgcn_s_setprio(1);
    #pragma unroll
    for (int s = 0; s < 2; ++s) {
      // B[kb]: k = kb*16 + 8*hi + j; one permlane32_swap per (quad-pair, p)
      bf16x8 B[4];
      #pragma unroll
      for (int kb = 0; kb < 4; ++kb) {
        int cm = kb >> 1, kbl = kb & 1;
        int4 wrd;
        #pragma unroll
        for (int p = 0; p < 2; ++p) {
          unsigned avv = P[s][cm][2 * kbl + 1][p];
          unsigned bvv = P[s][cm][2 * kbl][p];
          asm("v_permlane32_swap_b32 %0, %1" : "+v"(avv), "+v"(bvv));
          if (p == 0) { wrd.x = (int)bvv; wrd.z = (int)avv; }
          else        { wrd.y = (int)bvv; wrd.w = (int)avv; }
        }
        B[kb] = *(bf16x8*)&wrd;
      }

      f32x16 d0, d1;
      #pragma unroll
      for (int r = 0; r < 16; ++r) { d0[r] = 0.f; d1[r] = 0.f; }
      #pragma unroll
      for (int kb = 0; kb < 4; ++kb) {
        d0 = mfma32(af[0][kb], B[kb], d0);
        d1 = mfma32(af[1][kb], B[kb], d1);
      }

      // P = pack(d * e): reg 4q+s_ -> row 32cm+8q+4hi+s_
      #pragma unroll
      for (int qq = 0; qq < 4; ++qq)
        #pragma unroll
        for (int p = 0; p < 2; ++p) {
          P[s][0][qq][p] = cvtpk(d0[4 * qq + 2 * p] * ecur[0][qq][2 * p],
                                 d0[4 * qq + 2 * p + 1] * ecur[0][qq][2 * p + 1]);
          P[s][1][qq][p] = cvtpk(d1[4 * qq + 2 * p] * ecur[1][qq][2 * p],
                                 d1[4 * qq + 2 * p + 1] * ecur[1][qq][2 * p + 1]);
        }
    }
    __builtin_amdgcn_s_setprio(0);

    if ((i & 7) == 7) {  // rescale (i=7 and i=15; final one normalizes NTb)
      float m = 0.f;
      #pragma unroll
      for (int s = 0; s < 2; ++s)
        #pragma unroll
        for (int cm = 0; cm < 2; ++cm)
          #pragma unroll
          for (int qq = 0; qq < 4; ++qq)
            #pragma unroll
            for (int p = 0; p < 2; ++p) {
              unsigned u = P[s][cm][qq][p];
              m = fmaxf(m, __uint_as_float(u << 16));
              m = fmaxf(m, __uint_as_float(u & 0xffff0000u));
            }
      #pragma unroll
      for (int off = 1; off < 64; off <<= 1) m = fmaxf(m, __shfl_xor(m, off));
      float inv = 1.0f / m;
      #pragma unroll
      for (int s = 0; s < 2; ++s)
        #pragma unroll
        for (int cm = 0; cm < 2; ++cm)
          #pragma unroll
          for (int qq = 0; qq < 4; ++qq)
            #pragma unroll
            for (int p = 0; p < 2; ++p) {
              unsigned u = P[s][cm][qq][p];
              P[s][cm][qq][p] = cvtpk(__uint_as_float(u << 16) * inv,
                                      __uint_as_float(u & 0xffff0000u) * inv);
            }
      logscale += logf(m);
    }

    #pragma unroll
    for (int cm = 0; cm < 2; ++cm)
      #pragma unroll
      for (int qq = 0; qq < 4; ++qq) ecur[cm][qq] = enxt[cm][qq];
  }

  // store N_c bf16 row-major [row][col]
  unsigned short* No = (unsigned short*)(NTb + (((size_t)bS * 256 + c) << 12));
  #pragma unroll
  for (int s = 0; s < 2; ++s)
    #pragma unroll
    for (int cm = 0; cm < 2; ++cm)
      #pragma unroll
      for (int qq = 0; qq < 4; ++qq)
        #pragma unroll
        for (int p = 0; p < 2; ++p) {
          int row = 32 * cm + 8 * qq + 4 * hi + 2 * p;
          int col = s * 32 + l31;
          unsigned u = P[s][cm][qq][p];
          No[row * 64 + col] = (unsigned short)(u & 0xffffu);
          No[(row + 1) * 64 + col] = (unsigned short)(u >> 16);
        }

  // aux[b][chunk] = sum of colmax over chunk's t-range + chunk logscale
  float cs = (lane < nsteps) ? colmax2[tl][t0l + lane] : 0.f;
  #pragma unroll
  for (int off = 1; off < 64; off <<= 1) cs += __shfl_xor(cs, off);
  if (lane == 0) aux[(size_t)bS * 256 + c] = cs + logscale;
}

// ---------------- K5: merge 8 chunks -> group matrix (32 groups/batch) ------
__global__ __launch_bounds__(256) void mmm_merge_kernel(
    const short* __restrict__ NTb, const float* __restrict__ aux,
    float* __restrict__ G2T, float* __restrict__ auxg) {
  int g = blockIdx.x, b = blockIdx.y;
  int tid = threadIdx.x;
  int w = tid >> 6, lane = tid & 63;
  int wi = w >> 1, wj = w & 1;
  int lr = lane & 15, lg = lane >> 4;

  __shared__ __align__(16) short L[2][4096];
  __shared__ float wmax[4];

  for (int idx = tid; idx < 4096; idx += 256) {
    int j = idx >> 6, k = idx & 63;
    L[0][idx ^ ((j & 7) << 3)] = (j == k) ? (short)0x3F80 : (short)0;
  }
  __syncthreads();

  int cbase = b * 256 + g * 8;

  float logscale = 0.f;
  int cur = 0;
  f32x4 acc[2][2];

  bf16x8 apre[2][2];
  {
    const short* Mc = NTb + ((size_t)cbase << 12);
    #pragma unroll
    for (int rt = 0; rt < 2; ++rt)
      #pragma unroll
      for (int kc = 0; kc < 2; ++kc)
        apre[rt][kc] = *(const bf16x8*)&Mc[(wi * 32 + rt * 16 + lr) * 64 + kc * 32 + lg * 8];
  }

  for (int cc = 0; cc < 8; ++cc) {
    bf16x8 acur[2][2];
    #pragma unroll
    for (int rt = 0; rt < 2; ++rt)
      #pragma unroll
      for (int kc = 0; kc < 2; ++kc) acur[rt][kc] = apre[rt][kc];
    if (cc < 7) {
      const short* Mc = NTb + ((size_t)(cbase + cc + 1) << 12);
      #pragma unroll
      for (int rt = 0; rt < 2; ++rt)
        #pragma unroll
        for (int kc = 0; kc < 2; ++kc)
          apre[rt][kc] = *(const bf16x8*)&Mc[(wi * 32 + rt * 16 + lr) * 64 + kc * 32 + lg * 8];
    }

    logscale += aux[cbase + cc];

    bf16x8 bfr[2][2];
    #pragma unroll
    for (int ct = 0; ct < 2; ++ct) {
      int j = wj * 32 + ct * 16 + lr;
      int sw = (j & 7) << 3;
      #pragma unroll
      for (int kc = 0; kc < 2; ++kc)
        bfr[ct][kc] = *(const bf16x8*)&L[cur][(j * 64 + kc * 32 + lg * 8) ^ sw];
    }

    #pragma unroll
    for (int rt = 0; rt < 2; ++rt)
      #pragma unroll
      for (int ct = 0; ct < 2; ++ct) {
        f32x4 c = {0.f, 0.f, 0.f, 0.f};
        c = mfma16(acur[rt][0], bfr[ct][0], c);
        c = mfma16(acur[rt][1], bfr[ct][1], c);
        acc[rt][ct] = c;
      }

    if ((cc & 3) == 3) {  // rescale every 4th product (cc=3,7)
      float m = 0.f;
      #pragma unroll
      for (int rt = 0; rt < 2; ++rt)
        #pragma unroll
        for (int ct = 0; ct < 2; ++ct)
          #pragma unroll
          for (int r = 0; r < 4; ++r) m = fmaxf(m, acc[rt][ct][r]);
      #pragma unroll
      for (int off = 1; off < 64; off <<= 1) m = fmaxf(m, __shfl_xor(m, off));
      if (lane == 0) wmax[w] = m;
      __syncthreads();
      m = fmaxf(fmaxf(wmax[0], wmax[1]), fmaxf(wmax[2], wmax[3]));
      float inv = 1.0f / m;
      #pragma unroll
      for (int rt = 0; rt < 2; ++rt)
        #pragma unroll
        for (int ct = 0; ct < 2; ++ct) acc[rt][ct] *= inv;
      logscale += logf(m);
    }

    int nxt = cur ^ 1;
    unsigned* L32 = (unsigned*)&L[nxt][0];
    #pragma unroll
    for (int rt = 0; rt < 2; ++rt)
      #pragma unroll
      for (int ct = 0; ct < 2; ++ct) {
        int row0 = wi * 32 + rt * 16 + lg * 4;   // 4-aligned
        int col = wj * 32 + ct * 16 + lr;
        int sidx = (col * 64 + row0) ^ ((col & 7) << 3);  // XOR hits bits>=3 only
        L32[(sidx >> 1) + 0] = cvtpk(acc[rt][ct][0], acc[rt][ct][1]);
        L32[(sidx >> 1) + 1] = cvtpk(acc[rt][ct][2], acc[rt][ct][3]);
      }
    __syncthreads();
    cur = nxt;
  }

  float* Mo = G2T + (((size_t)b * 32 + g) << 12);
  #pragma unroll
  for (int rt = 0; rt < 2; ++rt)
    #pragma unroll
    for (int ct = 0; ct < 2; ++ct)
      #pragma unroll
      for (int r = 0; r < 4; ++r) {
        int row = wi * 32 + rt * 16 + lg * 4 + r;
        int col = wj * 32 + ct * 16 + lr;
        Mo[row * 64 + col] = acc[rt][ct][r];
      }

  if (w == 0 && lane == 0) auxg[b * 32 + g] = logscale;
}

// ---------------- K6: final combine (32 group matrices per batch) -----------
__global__ __launch_bounds__(64) void mmm_combine_kernel(
    const float* __restrict__ pi_logits, const float* __restrict__ ehat0,
    const float* __restrict__ cmax0, const float* __restrict__ G2T,
    const float* __restrict__ auxg, float* __restrict__ out) {
  int b = blockIdx.x, lane = threadIdx.x;
  __shared__ __align__(16) float alds[64];

  float pv = pi_logits[lane];
  float mx = pv;
  #pragma unroll
  for (int off = 1; off < 64; off <<= 1) mx = fmaxf(mx, __shfl_xor(mx, off));
  float pe = expf(pv - mx);
  float ps = pe;
  #pragma unroll
  for (int off = 1; off < 64; off <<= 1) ps += __shfl_xor(ps, off);

  float a = (pe / ps) * ehat0[b * 64 + lane];
  double logtot = (double)cmax0[b];
  alds[lane] = a;
  __builtin_amdgcn_wave_barrier();

  const float* Mb = G2T + (((size_t)b * 32) << 12) + lane * 64;
  f32x4 mc[16], mn[16];
  #pragma unroll
  for (int i = 0; i < 16; ++i) mc[i] = *(const f32x4*)&Mb[i * 4];

  for (int g = 0; g < 32; ++g) {
    if (g < 31) {
      const float* Mn = Mb + ((size_t)(g + 1) << 12);
      #pragma unroll
      for (int i = 0; i < 16; ++i) mn[i] = *(const f32x4*)&Mn[i * 4];
    }
    f32x4 a4 = {0.f, 0.f, 0.f, 0.f};
    #pragma unroll
    for (int i = 0; i < 16; ++i) {
      f32x4 av = *(const f32x4*)&alds[i * 4];
      a4 += mc[i] * av;
    }
    float acc = (a4[0] + a4[1]) + (a4[2] + a4[3]);
    float s = acc;
    #pragma unroll
    for (int off = 1; off < 64; off <<= 1) s += __shfl_xor(s, off);
    logtot += (double)(auxg[b * 32 + g] + logf(s));
    float an = acc / s;
    __builtin_amdgcn_wave_barrier();
    alds[lane] = an;
    __builtin_amdgcn_wave_barrier();
    #pragma unroll
    for (int i = 0; i < 16; ++i) mc[i] = mn[i];
  }
  if (lane == 0) out[b] = (float)logtot;
}

extern "C" void kernel_launch(void* const* d_in, const int* in_sizes, int n_in,
                              void* d_out, int out_size, void* d_ws, size_t ws_size,
                              hipStream_t stream) {
  const float* X      = (const float*)d_in[0];
  const float* pi_l   = (const float*)d_in[1];
  const float* tr_l   = (const float*)d_in[2];
  const float* wl     = (const float*)d_in[3];
  const float* means  = (const float*)d_in[4];
  const float* lvs    = (const float*)d_in[5];
  float* out = (float*)d_out;

  float* ws = (float*)d_ws;
  short* Gt      = (short*)ws;                 // 131072 shorts = 65536 f32
  float* const_c = ws + 65536;                 // 512
  short* WTbf    = (short*)(ws + 66048);       // 4096 shorts = 2048 f32
  float* ehat0   = ws + 68096;                 // 512 (8 b x 64 states, t=0)
  float* cmax0   = ws + 68608;                 // 8 (t=0 colmax per b)
  short* XeP     = (short*)(ws + 2198528);     // 16.8 MB -> ends 6392832
  short* NTb     = (short*)(ws + 6392832);     // 16.8 MB (NOT aliasing XeP!)
  float* aux     = ws + 10587136;              // 2048 (256 chunks x 8 b)
  float* G2T     = ws + 10591232;              // 1048576 (8 b x 32 g x 4096)
  float* auxg    = ws + 11639808;              // 256

  mmm_prep_fused<<<832, 256, 0, stream>>>(tr_l, means, lvs, wl, X,
                                          WTbf, Gt, const_c, XeP);
  mmm_emischunk_kernel<<<256, 512, 0, stream>>>(Gt, XeP, const_c, WTbf,
                                                NTb, aux, ehat0, cmax0);
  mmm_merge_kernel<<<dim3(32, 8), 256, 0, stream>>>(NTb, aux, G2T, auxg);
  mmm_combine_kernel<<<8, 64, 0, stream>>>(pi_l, ehat0, cmax0, G2T, auxg, out);
}